// Round 16
// baseline (204.112 us; speedup 1.0000x reference)
//
#include <hip/hip_runtime.h>
#include <hip/hip_bf16.h>
#include <stdint.h>

#define B_ 8
#define T_ 2048
#define C_ 384
#define H_ 6
#define D_ 64
#define M_ (B_*T_)   // 16384

typedef unsigned short u16;
typedef unsigned int u32;
typedef __attribute__((ext_vector_type(8))) short short8;
typedef __attribute__((ext_vector_type(4))) float floatx4;
typedef __attribute__((ext_vector_type(16))) float floatx16;

// softmax scale folded into stored Q: 0.125 * log2(e)
#define QSCALE 0.18033688011112042f

__device__ __forceinline__ u16 f2b(float f) {
  union { float f; unsigned u; } x; x.f = f;
  unsigned r = x.u + 0x7fffu + ((x.u >> 16) & 1u);  // round-nearest-even
  return (u16)(r >> 16);
}
__device__ __forceinline__ u32 pack_bf16(float a, float b) {
  union { __hip_bfloat162 h; u32 u; } x;
  x.h = __float22bfloat162_rn(float2{a, b});
  return x.u;
}
__device__ __forceinline__ uint4 pack8(const float4& lo, const float4& hi) {
  uint4 r;
  r.x = pack_bf16(lo.x, lo.y); r.y = pack_bf16(lo.z, lo.w);
  r.z = pack_bf16(hi.x, hi.y); r.w = pack_bf16(hi.z, hi.w);
  return r;
}

// v_permlane32_swap_b32: swaps a.hi(32 lanes) <-> b.lo(32 lanes).
__device__ __forceinline__ void plswap(u32& a, u32& b) {
  asm("v_permlane32_swap_b32 %0, %1" : "+v"(a), "+v"(b));
}

// bare v_exp_f32 — no libm range/denormal fixup (inputs bounded: |s|<=11.6)
__device__ __forceinline__ float fexp2(float x) {
#if __has_builtin(__builtin_amdgcn_exp2f)
  return __builtin_amdgcn_exp2f(x);
#else
  float r; asm("v_exp_f32 %0, %1" : "=v"(r) : "v"(x)); return r;
#endif
}

// packed f32x2 -> bf16x2 in ONE instruction (dst.lo = bf16(a), dst.hi = bf16(b))
__device__ __forceinline__ u32 cvtpk(float a, float b) {
  u32 r; asm("v_cvt_pk_bf16_f32 %0, %1, %2" : "=v"(r) : "v"(a), "v"(b)); return r;
}

// async global->LDS, 16B per lane.
__device__ __forceinline__ void gl_lds16(const u16* g, u16* l) {
#if __has_builtin(__builtin_amdgcn_global_load_lds)
  __builtin_amdgcn_global_load_lds(
      (const __attribute__((address_space(1))) unsigned int*)g,
      (__attribute__((address_space(3))) unsigned int*)l,
      16, 0, 0);
#else
  *reinterpret_cast<uint4*>(l + (threadIdx.x & 63) * 8) =
      *reinterpret_cast<const uint4*>(g);
#endif
}

// ---------------------------------------------------------------------------
// prep: one-time fp32 -> bf16 conversion of X and the four weight matrices.
// ---------------------------------------------------------------------------
__global__ __launch_bounds__(256) void prep_bf16(
    const float* __restrict__ x,
    const float* __restrict__ wq, const float* __restrict__ wk,
    const float* __restrict__ wv, const float* __restrict__ wo,
    u16* __restrict__ xb,
    u16* __restrict__ wqb, u16* __restrict__ wkb,
    u16* __restrict__ wvb, u16* __restrict__ wob)
{
  const int c = blockIdx.x * 256 + threadIdx.x;
  const float* src;
  u16* dst;
  int off;
  if (c < 786432) {                 // X: 6291456 / 8
    src = x; dst = xb; off = c;
  } else {
    int t = c - 786432;             // W: 147456 / 8 = 18432 chunks each
    int wsel = t / 18432;
    off = t - wsel * 18432;
    src = (wsel == 0) ? wq : (wsel == 1) ? wk : (wsel == 2) ? wv : wo;
    dst = (wsel == 0) ? wqb : (wsel == 1) ? wkb : (wsel == 2) ? wvb : wob;
  }
  const float4* p = reinterpret_cast<const float4*>(src + (size_t)off * 8);
  float4 lo = p[0], hi = p[1];
  *reinterpret_cast<uint4*>(dst + (size_t)off * 8) = pack8(lo, hi);
}

// ---------------------------------------------------------------------------
// Fused QKV projection — BK=32 (round-15) + round-16: __launch_bounds__
// (256, 4) to cap VGPR at 128 (was 132 -> 3 waves/SIMD).  LDS 40KB already
// allows 4 blocks/CU; registers were the binding constraint.
// ---------------------------------------------------------------------------
#define QKV_SBUF 10240   // u16 per buffer (20KB)

__global__ __launch_bounds__(256, 4) void qkv_fused(
    const u16* __restrict__ Xb,
    const u16* __restrict__ Wqb, const u16* __restrict__ Wkb, const u16* __restrict__ Wvb,
    const float* __restrict__ cosb, const float* __restrict__ sinb,
    u16* __restrict__ Qo, u16* __restrict__ Ko, u16* __restrict__ Vto)
{
  __shared__ __align__(16) u16 smem[2 * QKV_SBUF];   // 40 KB (epilogue: 18KB)

  // XCD remap: 768 wgs = 8 xcds x (16 m-blocks x 6 heads)
  const int id = blockIdx.x;
  const int xcd = id & 7;
  const int s = id >> 3;              // 0..95
  const int mb = xcd * 16 + s / 6;    // 0..127
  const int hh = s % 6;
  const int m0 = mb * 128;
  const int n0 = hh * 64;

  const int tid = threadIdx.x;
  const int w = tid >> 6;
  const int lane = tid & 63;
  const int quad = lane >> 4;
  const int c = lane & 15;

  const u16* Wz[3] = {Wqb, Wkb, Wvb};

  floatx4 acc[3][2][4];
#pragma unroll
  for (int z = 0; z < 3; z++)
#pragma unroll
    for (int i = 0; i < 2; i++)
#pragma unroll
      for (int j = 0; j < 4; j++) acc[z][i][j] = (floatx4){0.f, 0.f, 0.f, 0.f};

  const int lrow = lane >> 2;        // row within a 16-row chunk
  const int lcol = (lane & 3) * 8;   // 8-col (16B) offset within 32 cols

  // stage k-step k0 into buffer bb: A 8 chunks (wave: 2), B 12 (wave: 3)
  auto STAGE = [&](int bb, int k0) {
    u16* base = smem + bb * QKV_SBUF;
#pragma unroll
    for (int n = 0; n < 2; n++) {
      const int ch = w * 2 + n;
      gl_lds16(Xb + (size_t)(m0 + ch * 16 + lrow) * C_ + k0 + lcol, base + ch * 512);
    }
#pragma unroll
    for (int n = 0; n < 3; n++) {
      const int idx = w * 3 + n;       // 0..11
      const int z = idx >> 2;
      const int chz = idx & 3;
      gl_lds16(Wz[z] + (size_t)(n0 + chz * 16 + lrow) * C_ + k0 + lcol,
               base + 4096 + z * 2048 + chz * 512);
    }
  };

  STAGE(0, 0);
  __syncthreads();   // buf0 drained

  for (int i = 0; i < 12; i++) {
    const int bb = i & 1;
    if (i < 11) STAGE(bb ^ 1, (i + 1) * 32);   // async loads fly during compute

    const u16* As = smem + bb * QKV_SBUF;
    const u16* Bs0 = As + 4096;
    __builtin_amdgcn_s_setprio(1);
    short8 af2[2];
#pragma unroll
    for (int mi = 0; mi < 2; mi++)
      af2[mi] = *reinterpret_cast<const short8*>(
          As + (w * 32 + mi * 16 + c) * 32 + quad * 8);
#pragma unroll
    for (int z = 0; z < 3; z++) {
#pragma unroll
      for (int ni = 0; ni < 4; ni++) {
        short8 bf = *reinterpret_cast<const short8*>(
            Bs0 + z * 2048 + (ni * 16 + c) * 32 + quad * 8);
#pragma unroll
        for (int mi = 0; mi < 2; mi++)
          acc[z][mi][ni] = __builtin_amdgcn_mfma_f32_16x16x32_bf16(af2[mi], bf, acc[z][mi][ni], 0, 0, 0);
      }
    }
    __builtin_amdgcn_s_setprio(0);
    if (i < 11) __syncthreads();   // drain vmcnt -> buf[bb^1] ready
  }

  const int bb2 = m0 >> 11;
  const int tbase = m0 & (T_ - 1);

  // ---- V: register scatter to Vt[B][H][D][T] ----
  {
    const size_t vbase = ((size_t)(bb2 * H_ + hh)) * D_ * T_;
#pragma unroll
    for (int mi = 0; mi < 2; mi++) {
      int t = tbase + w * 32 + mi * 16 + quad * 4;
#pragma unroll
      for (int ni = 0; ni < 4; ni++) {
        int d = ni * 16 + c;
        ushort4 pk;
        pk.x = f2b(acc[2][mi][ni][0]); pk.y = f2b(acc[2][mi][ni][1]);
        pk.z = f2b(acc[2][mi][ni][2]); pk.w = f2b(acc[2][mi][ni][3]);
        *reinterpret_cast<ushort4*>(Vto + vbase + (size_t)d * T_ + t) = pk;
      }
    }
  }

  // ---- Q then K: lane-parallel RMS + RoPE, LDS transpose store ----
  u16* Ep = smem;
#pragma unroll
  for (int zz = 0; zz < 2; zz++) {
    __syncthreads();
#pragma unroll
    for (int mi = 0; mi < 2; mi++) {
      float ssr[4];
#pragma unroll
      for (int r = 0; r < 4; r++) {
        float s0 = acc[zz][mi][0][r], s1 = acc[zz][mi][1][r];
        float s2 = acc[zz][mi][2][r], s3 = acc[zz][mi][3][r];
        ssr[r] = s0 * s0 + s1 * s1 + s2 * s2 + s3 * s3;
      }
#pragma unroll
      for (int off = 1; off < 16; off <<= 1)
#pragma unroll
        for (int r = 0; r < 4; r++) ssr[r] += __shfl_xor(ssr[r], off, 64);
      int rowb = w * 32 + mi * 16 + quad * 4;
#pragma unroll
      for (int r = 0; r < 4; r++) {
        float scl = rsqrtf(ssr[r] * (1.0f / 64.0f) + 1e-5f);
        if (zz == 0) scl *= QSCALE;     // fold softmax scale into Q
        int t = tbase + rowb + r;
#pragma unroll
        for (int h2 = 0; h2 < 2; h2++) {
          float cs = cosb[t * 32 + h2 * 16 + c];
          float sn = sinb[t * 32 + h2 * 16 + c];
          float x1 = acc[zz][mi][h2][r];
          float x2 = acc[zz][mi][h2 + 2][r];
          Ep[(rowb + r) * 72 + h2 * 16 + c]       = f2b((x1 * cs + x2 * sn) * scl);
          Ep[(rowb + r) * 72 + (h2 + 2) * 16 + c] = f2b((x2 * cs - x1 * sn) * scl);
        }
      }
    }
    __syncthreads();
    {
      int row = tid >> 1, half = tid & 1;
      int t = tbase + row;
      u16* Og = (zz == 0) ? Qo : Ko;
      u16* dst = Og + (((size_t)(bb2 * H_ + hh)) * T_ + t) * D_ + half * 32;
#pragma unroll
      for (int i = 0; i < 4; i++)
        *reinterpret_cast<uint4*>(dst + i * 8) =
            *reinterpret_cast<const uint4*>(Ep + row * 72 + half * 32 + i * 8);
    }
  }
}

// ---------------------------------------------------------------------------
// MFMA flash attention — round-14 proven config (64.4us): stride-72 layout,
// identity slots, l ones-MFMA interleaved into PV, setprio.
// ---------------------------------------------------------------------------
#define ATT_LDA 72        // u16 row stride (144 B, 16B-aligned, bank-rotating)
#define ATT_VOFF 4608     // 64 rows * 72
#define ATT_BUF 9216      // K+V plane per buffer (u16)

__global__ __launch_bounds__(256, 3) void attn_mfma(
    const u16* __restrict__ Qg, const u16* __restrict__ Kg,
    const u16* __restrict__ Vtg, u16* __restrict__ Yg)
{
  __shared__ __align__(16) u16 smem[2 * ATT_BUF];   // 36864 B

  const int tid = threadIdx.x;
  const int w = tid >> 6;
  const int lane = tid & 63;
  const int hi = lane >> 5;
  const int lq = lane & 31;

  // XCD remap: 768 wgs = 8 xcds x (6 bh x 16 q-blocks)
  const int id = blockIdx.x;
  const int xcd = id & 7;
  const int slot = id >> 3;              // 0..95
  const int bh = xcd * 6 + (slot >> 4);  // 0..47
  const int q0 = (slot & 15) * 128;

  const size_t baseQK = (size_t)bh * T_ * D_;
  const size_t baseV  = (size_t)bh * D_ * T_;

  // Q fragments (B-operand): lane holds Q[q0+w*32+lq][ds*16 + hi*8 + j]
  short8 qf[4];
  {
    const u16* qp = Qg + baseQK + (size_t)(q0 + w * 32 + lq) * D_ + hi * 8;
#pragma unroll
    for (int d = 0; d < 4; d++)
      qf[d] = *reinterpret_cast<const short8*>(qp + d * 16);
  }

  floatx16 z16;
#pragma unroll
  for (int i = 0; i < 16; i++) z16[i] = 0.f;
  short8 vones;
#pragma unroll
  for (int i = 0; i < 8; i++) vones[i] = (short)0x3F80;

  // staging: 256 threads cover 64 rows x 2 x 16B chunks; identity slots
  const int sr = tid >> 2;
  const int sch = tid & 3;
  const int ko0 = sr * ATT_LDA + sch * 8;
  const int ko1 = sr * ATT_LDA + (sch + 4) * 8;
  const int vo0 = ATT_VOFF + ko0;
  const int vo1 = ATT_VOFF + ko1;
  const u16* kga = Kg + baseQK + (size_t)sr * D_ + sch * 8;
  const u16* vga = Vtg + baseV + (size_t)sr * T_ + sch * 8;

  // prologue: tile 0 -> regs -> buf0; then prefetch tile 1 into regs
  uint4 ka = *reinterpret_cast<const uint4*>(kga);
  uint4 kb = *reinterpret_cast<const uint4*>(kga + 32);
  uint4 va = *reinterpret_cast<const uint4*>(vga);
  uint4 vb = *reinterpret_cast<const uint4*>(vga + 32);
  *reinterpret_cast<uint4*>(smem + ko0) = ka;
  *reinterpret_cast<uint4*>(smem + ko1) = kb;
  *reinterpret_cast<uint4*>(smem + vo0) = va;
  *reinterpret_cast<uint4*>(smem + vo1) = vb;
  const u16* kload = kga + (size_t)64 * D_;
  const u16* vload = vga + 64;
  ka = *reinterpret_cast<const uint4*>(kload);
  kb = *reinterpret_cast<const uint4*>(kload + 32);
  va = *reinterpret_cast<const uint4*>(vload);
  vb = *reinterpret_cast<const uint4*>(vload + 32);
  kload += (size_t)64 * D_;
  vload += 64;

  floatx16 o0 = z16, o1 = z16;
  floatx16 l_acc = z16;

  // hoisted thread-invariant LDS read offsets (identity slots)
  int koff[2][4], voff[2][4];
#pragma unroll
  for (int ds = 0; ds < 4; ds++) {
    const int xr = ds * 2 + hi;
    koff[0][ds] = lq * ATT_LDA + xr * 8;
    koff[1][ds] = (32 + lq) * ATT_LDA + xr * 8;
    voff[0][ds] = ATT_VOFF + lq * ATT_LDA + xr * 8;
    voff[1][ds] = ATT_VOFF + (32 + lq) * ATT_LDA + xr * 8;
  }

  for (int kt = 0; kt < 32; kt++) {
    __syncthreads();   // buf[kt&1] fully written; buf[(kt+1)&1] fully read

    // write prefetched tile kt+1 into the other buffer; issue loads kt+2
    if (kt < 31) {
      u16* wb = smem + ((kt + 1) & 1) * ATT_BUF;
      *reinterpret_cast<uint4*>(wb + ko0) = ka;
      *reinterpret_cast<uint4*>(wb + ko1) = kb;
      *reinterpret_cast<uint4*>(wb + vo0) = va;
      *reinterpret_cast<uint4*>(wb + vo1) = vb;
      if (kt < 30) {
        ka = *reinterpret_cast<const uint4*>(kload);
        kb = *reinterpret_cast<const uint4*>(kload + 32);
        va = *reinterpret_cast<const uint4*>(vload);
        vb = *reinterpret_cast<const uint4*>(vload + 32);
        kload += (size_t)64 * D_;
        vload += 64;
      }
    }

    const u16* Ksb = smem + (kt & 1) * ATT_BUF;

    // ---- QK^T (swapped): st = K * Q^T, col = q (lane-local), rows = t ----
    floatx16 st0, st1;
    __builtin_amdgcn_s_setprio(1);
    {
      short8 kf0 = *reinterpret_cast<const short8*>(Ksb + koff[0][0]);
      short8 kf1 = *reinterpret_cast<const short8*>(Ksb + koff[1][0]);
      st0 = __builtin_amdgcn_mfma_f32_32x32x16_bf16(kf0, qf[0], z16, 0, 0, 0);
      st1 = __builtin_amdgcn_mfma_f32_32x32x16_bf16(kf1, qf[0], z16, 0, 0, 0);
    }
#pragma unroll
    for (int ds = 1; ds < 4; ds++) {
      short8 kf0 = *reinterpret_cast<const short8*>(Ksb + koff[0][ds]);
      short8 kf1 = *reinterpret_cast<const short8*>(Ksb + koff[1][ds]);
      st0 = __builtin_amdgcn_mfma_f32_32x32x16_bf16(kf0, qf[ds], st0, 0, 0, 0);
      st1 = __builtin_amdgcn_mfma_f32_32x32x16_bf16(kf1, qf[ds], st1, 0, 0, 0);
    }
    __builtin_amdgcn_s_setprio(0);

    // ---- softmax: p = exp2(s), bare v_exp_f32 ----
#pragma unroll
    for (int r = 0; r < 16; r++) {
      st0[r] = fexp2(st0[r]);
      st1[r] = fexp2(st1[r]);
    }

    // ---- P -> bf16 A-fragments: 16 v_cvt_pk + 8 permlane32_swap ----
    short8 pa[4];
#pragma unroll
    for (int ks = 0; ks < 4; ks++) {
      const floatx16& s = (ks < 2) ? st0 : st1;
      const int rb = (ks & 1) * 8;
      u32 ca = cvtpk(s[rb + 0], s[rb + 1]);
      u32 cb = cvtpk(s[rb + 2], s[rb + 3]);
      u32 cc = cvtpk(s[rb + 4], s[rb + 5]);
      u32 cd = cvtpk(s[rb + 6], s[rb + 7]);
      plswap(ca, cc);
      plswap(cb, cd);
      short8 pf;
      u32* pfu = reinterpret_cast<u32*>(&pf);
      pfu[0] = ca; pfu[1] = cb; pfu[2] = cc; pfu[3] = cd;
      pa[ks] = pf;
    }

    // ---- PV + l row-sums: 3 independent chains (o0/o1/l) interleaved ----
    __builtin_amdgcn_s_setprio(1);
#pragma unroll
    for (int ks = 0; ks < 4; ks++) {
      short8 vf0 = *reinterpret_cast<const short8*>(Ksb + voff[0][ks]);
      short8 vf1 = *reinterpret_cast<const short8*>(Ksb + voff[1][ks]);
      o0 = __builtin_amdgcn_mfma_f32_32x32x16_bf16(pa[ks], vf0, o0, 0, 0, 0);
      o1 = __builtin_amdgcn_mfma_f32_32x32x16_bf16(pa[ks], vf1, o1, 0, 0, 0);
      l_acc = __builtin_amdgcn_mfma_f32_32x32x16_bf16(pa[ks], vones, l_acc, 0, 0, 0);
    }
    __builtin_amdgcn_s_setprio(0);
  }

  // normalization: l_acc[r] holds l for exactly the q-row o[r] holds
  float invr[16];
#pragma unroll
  for (int r = 0; r < 16; r++) invr[r] = __builtin_amdgcn_rcpf(l_acc[r]);

  __syncthreads();   // done with K/V buffers; reuse smem for epilogue
  u16* Ep = smem + w * (32 * 72);
#pragma unroll
  for (int nt = 0; nt < 2; nt++) {
    const floatx16& o = nt ? o1 : o0;
#pragma unroll
    for (int r = 0; r < 16; r++) {
      const int rl = (r & 3) + 8 * (r >> 2) + 4 * hi;
      Ep[rl * 72 + nt * 32 + lq] = f2b(o[r] * invr[r]);
    }
  }
  __syncthreads();
  {
    const int row = tid >> 1, half = tid & 1;   // 128 rows x 2 halves of 64B
    const u16* src = smem + (row >> 5) * (32 * 72) + (row & 31) * 72 + half * 32;
    const int t = q0 + row;
    const int b = bh / H_, h = bh % H_;
    const size_t yi = ((size_t)b * T_ + t) * C_ + (size_t)h * 64 + half * 32;
#pragma unroll
    for (int i = 0; i < 4; i++)
      *reinterpret_cast<uint4*>(Yg + yi + i * 8) =
          *reinterpret_cast<const uint4*>(src + i * 8);
  }
}

// ---------------------------------------------------------------------------
// Out projection — BK=32, 4 blocks/CU (round-15 proven).
// ---------------------------------------------------------------------------
#define OUT_SBUF 6144    // u16 per buffer (12KB)

__global__ __launch_bounds__(256, 4) void out_mfma(
    const u16* __restrict__ Xb, const u16* __restrict__ Wfb, float* __restrict__ Og)
{
  __shared__ __align__(16) u16 smem[17408];   // buffers at 0/6144; fp32 Ep 34816B

  const int id = blockIdx.x;
  const int xcd = id & 7;
  const int s = id >> 3;              // 0..95
  const int m0 = (xcd * 16 + s / 6) * 128;
  const int n0 = (s % 6) * 64;

  const int tid = threadIdx.x;
  const int w = tid >> 6;
  const int lane = tid & 63;
  const int quad = lane >> 4;
  const int c = lane & 15;

  floatx4 acc[2][4];
#pragma unroll
  for (int i = 0; i < 2; i++)
#pragma unroll
    for (int j = 0; j < 4; j++) acc[i][j] = (floatx4){0.f, 0.f, 0.f, 0.f};

  const int lrow = lane >> 2;        // row within a 16-row chunk
  const int lcol = (lane & 3) * 8;   // 8-col offset within 32 cols

  auto STAGE = [&](int bb, int k0) {
    u16* base = smem + bb * OUT_SBUF;
#pragma unroll
    for (int n = 0; n < 2; n++) {
      const int ch = w * 2 + n;
      gl_lds16(Xb + (size_t)(m0 + ch * 16 + lrow) * C_ + k0 + lcol, base + ch * 512);
    }
    gl_lds16(Wfb + (size_t)(n0 + w * 16 + lrow) * C_ + k0 + lcol,
             base + 4096 + w * 512);
  };

  STAGE(0, 0);
  __syncthreads();

  for (int i = 0; i < 12; i++) {
    const int bb = i & 1;
    if (i < 11) STAGE(bb ^ 1, (i + 1) * 32);

    const u16* As = smem + bb * OUT_SBUF;
    const u16* Bs = As + 4096;
    __builtin_amdgcn_s_setprio(1);
    short8 af[2], bf[4];
#pragma unroll
    for (int mi = 0; mi < 2; mi++)
      af[mi] = *reinterpret_cast<const short8*>(
          As + (w * 32 + mi * 16 + c) * 32 + quad * 8);
#pragma unroll
    for (int ni = 0; ni < 4; ni++)
      bf[ni] = *reinterpret_cast<const short8*>(
          Bs + (ni * 16 + c) * 32 + quad * 8);
#pragma unroll
    for (int mi = 0; mi < 2; mi++)
#pragma unroll
      for (int ni = 0; ni < 4; ni++)
        acc[mi][ni] = __builtin_amdgcn_mfma_f32_16x16x32_bf16(af[mi], bf[ni], acc[mi][ni], 0, 0, 0);
    __builtin_amdgcn_s_setprio(0);
    if (i < 11) __syncthreads();
  }

  __syncthreads();
  float* Ep = reinterpret_cast<float*>(smem) + w * (32 * 68);
#pragma unroll
  for (int mi = 0; mi < 2; mi++)
#pragma unroll
    for (int ni = 0; ni < 4; ni++) {
      int rw = mi * 16 + quad * 4;
      int col = ni * 16 + c;
#pragma unroll
      for (int r = 0; r < 4; r++)
        Ep[(rw + r) * 68 + col] = acc[mi][ni][r];
    }
  __syncthreads();
  {
    int rw2 = lane >> 1, half = lane & 1;
    const float* src = Ep + rw2 * 68 + half * 32;
    float* dst = Og + (size_t)(m0 + w * 32 + rw2) * C_ + n0 + half * 32;
#pragma unroll
    for (int i = 0; i < 8; i++)
      *reinterpret_cast<float4*>(dst + i * 4) =
          *reinterpret_cast<const float4*>(src + i * 4);
  }
}

// ---------------------------------------------------------------------------
extern "C" void kernel_launch(void* const* d_in, const int* in_sizes, int n_in,
                              void* d_out, int out_size, void* d_ws, size_t ws_size,
                              hipStream_t stream) {
  (void)in_sizes; (void)n_in; (void)out_size; (void)ws_size;
  const float* x    = (const float*)d_in[0];
  const float* Wq   = (const float*)d_in[1];
  const float* Wk   = (const float*)d_in[2];
  const float* Wv   = (const float*)d_in[3];
  const float* Wo   = (const float*)d_in[4];
  const float* cosb = (const float*)d_in[5];
  const float* sinb = (const float*)d_in[6];

  const size_t MC = (size_t)M_ * C_;    // 6291456
  u16* ws = (u16*)d_ws;
  u16* Q   = ws;                        // [B][H][T][D] bf16 (pre-scaled)
  u16* K   = Q + MC;
  u16* Vt  = K + MC;                    // [B][H][D][T] bf16
  u16* Y   = Vt + MC;                   // attn out [B*T][C] bf16; doubles as Xb
  u16* Xb  = Y;                         // bf16 X (consumed by qkv before attn writes Y)
  u16* Wb  = Y + MC;                    // 4 x 147456 bf16 weights
  u16* Wqb = Wb;
  u16* Wkb = Wb + 147456;
  u16* Wvb = Wb + 2 * 147456;
  u16* Wob = Wb + 3 * 147456;
  float* out = (float*)d_out;

  prep_bf16<<<3360, 256, 0, stream>>>(x, Wq, Wk, Wv, Wo, Xb, Wqb, Wkb, Wvb, Wob);

  qkv_fused<<<768, 256, 0, stream>>>(Xb, Wqb, Wkb, Wvb, cosb, sinb, Q, K, Vt);

  attn_mfma<<<768, 256, 0, stream>>>(Q, K, Vt, Y);

  out_mfma<<<768, 256, 0, stream>>>(Y, Wob, out);
}

// Round 17
// 198.476 us; speedup vs baseline: 1.0284x; 1.0284x over previous
//
#include <hip/hip_runtime.h>
#include <hip/hip_bf16.h>
#include <stdint.h>

#define B_ 8
#define T_ 2048
#define C_ 384
#define H_ 6
#define D_ 64
#define M_ (B_*T_)   // 16384

typedef unsigned short u16;
typedef unsigned int u32;
typedef __attribute__((ext_vector_type(8))) short short8;
typedef __attribute__((ext_vector_type(4))) float floatx4;
typedef __attribute__((ext_vector_type(16))) float floatx16;

// softmax scale folded into stored Q: 0.125 * log2(e)
#define QSCALE 0.18033688011112042f

__device__ __forceinline__ u16 f2b(float f) {
  union { float f; unsigned u; } x; x.f = f;
  unsigned r = x.u + 0x7fffu + ((x.u >> 16) & 1u);  // round-nearest-even
  return (u16)(r >> 16);
}
__device__ __forceinline__ u32 pack_bf16(float a, float b) {
  union { __hip_bfloat162 h; u32 u; } x;
  x.h = __float22bfloat162_rn(float2{a, b});
  return x.u;
}
__device__ __forceinline__ uint4 pack8(const float4& lo, const float4& hi) {
  uint4 r;
  r.x = pack_bf16(lo.x, lo.y); r.y = pack_bf16(lo.z, lo.w);
  r.z = pack_bf16(hi.x, hi.y); r.w = pack_bf16(hi.z, hi.w);
  return r;
}

// v_permlane32_swap_b32: swaps a.hi(32 lanes) <-> b.lo(32 lanes).
__device__ __forceinline__ void plswap(u32& a, u32& b) {
  asm("v_permlane32_swap_b32 %0, %1" : "+v"(a), "+v"(b));
}

// bare v_exp_f32 — no libm range/denormal fixup (inputs bounded: |s|<=11.6)
__device__ __forceinline__ float fexp2(float x) {
#if __has_builtin(__builtin_amdgcn_exp2f)
  return __builtin_amdgcn_exp2f(x);
#else
  float r; asm("v_exp_f32 %0, %1" : "=v"(r) : "v"(x)); return r;
#endif
}

// packed f32x2 -> bf16x2 in ONE instruction (dst.lo = bf16(a), dst.hi = bf16(b))
__device__ __forceinline__ u32 cvtpk(float a, float b) {
  u32 r; asm("v_cvt_pk_bf16_f32 %0, %1, %2" : "=v"(r) : "v"(a), "v"(b)); return r;
}

// async global->LDS, 16B per lane.
__device__ __forceinline__ void gl_lds16(const u16* g, u16* l) {
#if __has_builtin(__builtin_amdgcn_global_load_lds)
  __builtin_amdgcn_global_load_lds(
      (const __attribute__((address_space(1))) unsigned int*)g,
      (__attribute__((address_space(3))) unsigned int*)l,
      16, 0, 0);
#else
  *reinterpret_cast<uint4*>(l + (threadIdx.x & 63) * 8) =
      *reinterpret_cast<const uint4*>(g);
#endif
}

// ---------------------------------------------------------------------------
// prep: one-time fp32 -> bf16 conversion of X and the four weight matrices.
// ---------------------------------------------------------------------------
__global__ __launch_bounds__(256) void prep_bf16(
    const float* __restrict__ x,
    const float* __restrict__ wq, const float* __restrict__ wk,
    const float* __restrict__ wv, const float* __restrict__ wo,
    u16* __restrict__ xb,
    u16* __restrict__ wqb, u16* __restrict__ wkb,
    u16* __restrict__ wvb, u16* __restrict__ wob)
{
  const int c = blockIdx.x * 256 + threadIdx.x;
  const float* src;
  u16* dst;
  int off;
  if (c < 786432) {                 // X: 6291456 / 8
    src = x; dst = xb; off = c;
  } else {
    int t = c - 786432;             // W: 147456 / 8 = 18432 chunks each
    int wsel = t / 18432;
    off = t - wsel * 18432;
    src = (wsel == 0) ? wq : (wsel == 1) ? wk : (wsel == 2) ? wv : wo;
    dst = (wsel == 0) ? wqb : (wsel == 1) ? wkb : (wsel == 2) ? wvb : wob;
  }
  const float4* p = reinterpret_cast<const float4*>(src + (size_t)off * 8);
  float4 lo = p[0], hi = p[1];
  *reinterpret_cast<uint4*>(dst + (size_t)off * 8) = pack8(lo, hi);
}

// ---------------------------------------------------------------------------
// Fused QKV projection — round-15 proven config: BK=32, dbuf 40KB,
// STAGE-before-compute, one barrier per step, setprio, (256,3).
// VGPR=132 is irreducible here (round-16 (256,4) experiment -> spills).
// ---------------------------------------------------------------------------
#define QKV_SBUF 10240   // u16 per buffer (20KB)

__global__ __launch_bounds__(256, 3) void qkv_fused(
    const u16* __restrict__ Xb,
    const u16* __restrict__ Wqb, const u16* __restrict__ Wkb, const u16* __restrict__ Wvb,
    const float* __restrict__ cosb, const float* __restrict__ sinb,
    u16* __restrict__ Qo, u16* __restrict__ Ko, u16* __restrict__ Vto)
{
  __shared__ __align__(16) u16 smem[2 * QKV_SBUF];   // 40 KB (epilogue: 18KB)

  // XCD remap: 768 wgs = 8 xcds x (16 m-blocks x 6 heads)
  const int id = blockIdx.x;
  const int xcd = id & 7;
  const int s = id >> 3;              // 0..95
  const int mb = xcd * 16 + s / 6;    // 0..127
  const int hh = s % 6;
  const int m0 = mb * 128;
  const int n0 = hh * 64;

  const int tid = threadIdx.x;
  const int w = tid >> 6;
  const int lane = tid & 63;
  const int quad = lane >> 4;
  const int c = lane & 15;

  const u16* Wz[3] = {Wqb, Wkb, Wvb};

  floatx4 acc[3][2][4];
#pragma unroll
  for (int z = 0; z < 3; z++)
#pragma unroll
    for (int i = 0; i < 2; i++)
#pragma unroll
      for (int j = 0; j < 4; j++) acc[z][i][j] = (floatx4){0.f, 0.f, 0.f, 0.f};

  const int lrow = lane >> 2;        // row within a 16-row chunk
  const int lcol = (lane & 3) * 8;   // 8-col (16B) offset within 32 cols

  // stage k-step k0 into buffer bb: A 8 chunks (wave: 2), B 12 (wave: 3)
  auto STAGE = [&](int bb, int k0) {
    u16* base = smem + bb * QKV_SBUF;
#pragma unroll
    for (int n = 0; n < 2; n++) {
      const int ch = w * 2 + n;
      gl_lds16(Xb + (size_t)(m0 + ch * 16 + lrow) * C_ + k0 + lcol, base + ch * 512);
    }
#pragma unroll
    for (int n = 0; n < 3; n++) {
      const int idx = w * 3 + n;       // 0..11
      const int z = idx >> 2;
      const int chz = idx & 3;
      gl_lds16(Wz[z] + (size_t)(n0 + chz * 16 + lrow) * C_ + k0 + lcol,
               base + 4096 + z * 2048 + chz * 512);
    }
  };

  STAGE(0, 0);
  __syncthreads();   // buf0 drained

  for (int i = 0; i < 12; i++) {
    const int bb = i & 1;
    if (i < 11) STAGE(bb ^ 1, (i + 1) * 32);   // async loads fly during compute

    const u16* As = smem + bb * QKV_SBUF;
    const u16* Bs0 = As + 4096;
    __builtin_amdgcn_s_setprio(1);
    short8 af2[2];
#pragma unroll
    for (int mi = 0; mi < 2; mi++)
      af2[mi] = *reinterpret_cast<const short8*>(
          As + (w * 32 + mi * 16 + c) * 32 + quad * 8);
#pragma unroll
    for (int z = 0; z < 3; z++) {
#pragma unroll
      for (int ni = 0; ni < 4; ni++) {
        short8 bf = *reinterpret_cast<const short8*>(
            Bs0 + z * 2048 + (ni * 16 + c) * 32 + quad * 8);
#pragma unroll
        for (int mi = 0; mi < 2; mi++)
          acc[z][mi][ni] = __builtin_amdgcn_mfma_f32_16x16x32_bf16(af2[mi], bf, acc[z][mi][ni], 0, 0, 0);
      }
    }
    __builtin_amdgcn_s_setprio(0);
    if (i < 11) __syncthreads();   // drain vmcnt -> buf[bb^1] ready
  }

  const int bb2 = m0 >> 11;
  const int tbase = m0 & (T_ - 1);

  // ---- V: register scatter to Vt[B][H][D][T] ----
  {
    const size_t vbase = ((size_t)(bb2 * H_ + hh)) * D_ * T_;
#pragma unroll
    for (int mi = 0; mi < 2; mi++) {
      int t = tbase + w * 32 + mi * 16 + quad * 4;
#pragma unroll
      for (int ni = 0; ni < 4; ni++) {
        int d = ni * 16 + c;
        ushort4 pk;
        pk.x = f2b(acc[2][mi][ni][0]); pk.y = f2b(acc[2][mi][ni][1]);
        pk.z = f2b(acc[2][mi][ni][2]); pk.w = f2b(acc[2][mi][ni][3]);
        *reinterpret_cast<ushort4*>(Vto + vbase + (size_t)d * T_ + t) = pk;
      }
    }
  }

  // ---- Q then K: lane-parallel RMS + RoPE, LDS transpose store ----
  u16* Ep = smem;
#pragma unroll
  for (int zz = 0; zz < 2; zz++) {
    __syncthreads();
#pragma unroll
    for (int mi = 0; mi < 2; mi++) {
      float ssr[4];
#pragma unroll
      for (int r = 0; r < 4; r++) {
        float s0 = acc[zz][mi][0][r], s1 = acc[zz][mi][1][r];
        float s2 = acc[zz][mi][2][r], s3 = acc[zz][mi][3][r];
        ssr[r] = s0 * s0 + s1 * s1 + s2 * s2 + s3 * s3;
      }
#pragma unroll
      for (int off = 1; off < 16; off <<= 1)
#pragma unroll
        for (int r = 0; r < 4; r++) ssr[r] += __shfl_xor(ssr[r], off, 64);
      int rowb = w * 32 + mi * 16 + quad * 4;
#pragma unroll
      for (int r = 0; r < 4; r++) {
        float scl = rsqrtf(ssr[r] * (1.0f / 64.0f) + 1e-5f);
        if (zz == 0) scl *= QSCALE;     // fold softmax scale into Q
        int t = tbase + rowb + r;
#pragma unroll
        for (int h2 = 0; h2 < 2; h2++) {
          float cs = cosb[t * 32 + h2 * 16 + c];
          float sn = sinb[t * 32 + h2 * 16 + c];
          float x1 = acc[zz][mi][h2][r];
          float x2 = acc[zz][mi][h2 + 2][r];
          Ep[(rowb + r) * 72 + h2 * 16 + c]       = f2b((x1 * cs + x2 * sn) * scl);
          Ep[(rowb + r) * 72 + (h2 + 2) * 16 + c] = f2b((x2 * cs - x1 * sn) * scl);
        }
      }
    }
    __syncthreads();
    {
      int row = tid >> 1, half = tid & 1;
      int t = tbase + row;
      u16* Og = (zz == 0) ? Qo : Ko;
      u16* dst = Og + (((size_t)(bb2 * H_ + hh)) * T_ + t) * D_ + half * 32;
#pragma unroll
      for (int i = 0; i < 4; i++)
        *reinterpret_cast<uint4*>(dst + i * 8) =
            *reinterpret_cast<const uint4*>(Ep + row * 72 + half * 32 + i * 8);
    }
  }
}

// ---------------------------------------------------------------------------
// MFMA flash attention — round-14 proven config (63.3-64.4us): stride-72
// layout, identity slots, l ones-MFMA interleaved into PV, setprio.
// ---------------------------------------------------------------------------
#define ATT_LDA 72        // u16 row stride (144 B, 16B-aligned, bank-rotating)
#define ATT_VOFF 4608     // 64 rows * 72
#define ATT_BUF 9216      // K+V plane per buffer (u16)

__global__ __launch_bounds__(256, 3) void attn_mfma(
    const u16* __restrict__ Qg, const u16* __restrict__ Kg,
    const u16* __restrict__ Vtg, u16* __restrict__ Yg)
{
  __shared__ __align__(16) u16 smem[2 * ATT_BUF];   // 36864 B

  const int tid = threadIdx.x;
  const int w = tid >> 6;
  const int lane = tid & 63;
  const int hi = lane >> 5;
  const int lq = lane & 31;

  // XCD remap: 768 wgs = 8 xcds x (6 bh x 16 q-blocks)
  const int id = blockIdx.x;
  const int xcd = id & 7;
  const int slot = id >> 3;              // 0..95
  const int bh = xcd * 6 + (slot >> 4);  // 0..47
  const int q0 = (slot & 15) * 128;

  const size_t baseQK = (size_t)bh * T_ * D_;
  const size_t baseV  = (size_t)bh * D_ * T_;

  // Q fragments (B-operand): lane holds Q[q0+w*32+lq][ds*16 + hi*8 + j]
  short8 qf[4];
  {
    const u16* qp = Qg + baseQK + (size_t)(q0 + w * 32 + lq) * D_ + hi * 8;
#pragma unroll
    for (int d = 0; d < 4; d++)
      qf[d] = *reinterpret_cast<const short8*>(qp + d * 16);
  }

  floatx16 z16;
#pragma unroll
  for (int i = 0; i < 16; i++) z16[i] = 0.f;
  short8 vones;
#pragma unroll
  for (int i = 0; i < 8; i++) vones[i] = (short)0x3F80;

  // staging: 256 threads cover 64 rows x 2 x 16B chunks; identity slots
  const int sr = tid >> 2;
  const int sch = tid & 3;
  const int ko0 = sr * ATT_LDA + sch * 8;
  const int ko1 = sr * ATT_LDA + (sch + 4) * 8;
  const int vo0 = ATT_VOFF + ko0;
  const int vo1 = ATT_VOFF + ko1;
  const u16* kga = Kg + baseQK + (size_t)sr * D_ + sch * 8;
  const u16* vga = Vtg + baseV + (size_t)sr * T_ + sch * 8;

  // prologue: tile 0 -> regs -> buf0; then prefetch tile 1 into regs
  uint4 ka = *reinterpret_cast<const uint4*>(kga);
  uint4 kb = *reinterpret_cast<const uint4*>(kga + 32);
  uint4 va = *reinterpret_cast<const uint4*>(vga);
  uint4 vb = *reinterpret_cast<const uint4*>(vga + 32);
  *reinterpret_cast<uint4*>(smem + ko0) = ka;
  *reinterpret_cast<uint4*>(smem + ko1) = kb;
  *reinterpret_cast<uint4*>(smem + vo0) = va;
  *reinterpret_cast<uint4*>(smem + vo1) = vb;
  const u16* kload = kga + (size_t)64 * D_;
  const u16* vload = vga + 64;
  ka = *reinterpret_cast<const uint4*>(kload);
  kb = *reinterpret_cast<const uint4*>(kload + 32);
  va = *reinterpret_cast<const uint4*>(vload);
  vb = *reinterpret_cast<const uint4*>(vload + 32);
  kload += (size_t)64 * D_;
  vload += 64;

  floatx16 o0 = z16, o1 = z16;
  floatx16 l_acc = z16;

  // hoisted thread-invariant LDS read offsets (identity slots)
  int koff[2][4], voff[2][4];
#pragma unroll
  for (int ds = 0; ds < 4; ds++) {
    const int xr = ds * 2 + hi;
    koff[0][ds] = lq * ATT_LDA + xr * 8;
    koff[1][ds] = (32 + lq) * ATT_LDA + xr * 8;
    voff[0][ds] = ATT_VOFF + lq * ATT_LDA + xr * 8;
    voff[1][ds] = ATT_VOFF + (32 + lq) * ATT_LDA + xr * 8;
  }

  for (int kt = 0; kt < 32; kt++) {
    __syncthreads();   // buf[kt&1] fully written; buf[(kt+1)&1] fully read

    // write prefetched tile kt+1 into the other buffer; issue loads kt+2
    if (kt < 31) {
      u16* wb = smem + ((kt + 1) & 1) * ATT_BUF;
      *reinterpret_cast<uint4*>(wb + ko0) = ka;
      *reinterpret_cast<uint4*>(wb + ko1) = kb;
      *reinterpret_cast<uint4*>(wb + vo0) = va;
      *reinterpret_cast<uint4*>(wb + vo1) = vb;
      if (kt < 30) {
        ka = *reinterpret_cast<const uint4*>(kload);
        kb = *reinterpret_cast<const uint4*>(kload + 32);
        va = *reinterpret_cast<const uint4*>(vload);
        vb = *reinterpret_cast<const uint4*>(vload + 32);
        kload += (size_t)64 * D_;
        vload += 64;
      }
    }

    const u16* Ksb = smem + (kt & 1) * ATT_BUF;

    // ---- QK^T (swapped): st = K * Q^T, col = q (lane-local), rows = t ----
    floatx16 st0, st1;
    __builtin_amdgcn_s_setprio(1);
    {
      short8 kf0 = *reinterpret_cast<const short8*>(Ksb + koff[0][0]);
      short8 kf1 = *reinterpret_cast<const short8*>(Ksb + koff[1][0]);
      st0 = __builtin_amdgcn_mfma_f32_32x32x16_bf16(kf0, qf[0], z16, 0, 0, 0);
      st1 = __builtin_amdgcn_mfma_f32_32x32x16_bf16(kf1, qf[0], z16, 0, 0, 0);
    }
#pragma unroll
    for (int ds = 1; ds < 4; ds++) {
      short8 kf0 = *reinterpret_cast<const short8*>(Ksb + koff[0][ds]);
      short8 kf1 = *reinterpret_cast<const short8*>(Ksb + koff[1][ds]);
      st0 = __builtin_amdgcn_mfma_f32_32x32x16_bf16(kf0, qf[ds], st0, 0, 0, 0);
      st1 = __builtin_amdgcn_mfma_f32_32x32x16_bf16(kf1, qf[ds], st1, 0, 0, 0);
    }
    __builtin_amdgcn_s_setprio(0);

    // ---- softmax: p = exp2(s), bare v_exp_f32 ----
#pragma unroll
    for (int r = 0; r < 16; r++) {
      st0[r] = fexp2(st0[r]);
      st1[r] = fexp2(st1[r]);
    }

    // ---- P -> bf16 A-fragments: 16 v_cvt_pk + 8 permlane32_swap ----
    short8 pa[4];
#pragma unroll
    for (int ks = 0; ks < 4; ks++) {
      const floatx16& s = (ks < 2) ? st0 : st1;
      const int rb = (ks & 1) * 8;
      u32 ca = cvtpk(s[rb + 0], s[rb + 1]);
      u32 cb = cvtpk(s[rb + 2], s[rb + 3]);
      u32 cc = cvtpk(s[rb + 4], s[rb + 5]);
      u32 cd = cvtpk(s[rb + 6], s[rb + 7]);
      plswap(ca, cc);
      plswap(cb, cd);
      short8 pf;
      u32* pfu = reinterpret_cast<u32*>(&pf);
      pfu[0] = ca; pfu[1] = cb; pfu[2] = cc; pfu[3] = cd;
      pa[ks] = pf;
    }

    // ---- PV + l row-sums: 3 independent chains (o0/o1/l) interleaved ----
    __builtin_amdgcn_s_setprio(1);
#pragma unroll
    for (int ks = 0; ks < 4; ks++) {
      short8 vf0 = *reinterpret_cast<const short8*>(Ksb + voff[0][ks]);
      short8 vf1 = *reinterpret_cast<const short8*>(Ksb + voff[1][ks]);
      o0 = __builtin_amdgcn_mfma_f32_32x32x16_bf16(pa[ks], vf0, o0, 0, 0, 0);
      o1 = __builtin_amdgcn_mfma_f32_32x32x16_bf16(pa[ks], vf1, o1, 0, 0, 0);
      l_acc = __builtin_amdgcn_mfma_f32_32x32x16_bf16(pa[ks], vones, l_acc, 0, 0, 0);
    }
    __builtin_amdgcn_s_setprio(0);
  }

  // normalization: l_acc[r] holds l for exactly the q-row o[r] holds
  float invr[16];
#pragma unroll
  for (int r = 0; r < 16; r++) invr[r] = __builtin_amdgcn_rcpf(l_acc[r]);

  __syncthreads();   // done with K/V buffers; reuse smem for epilogue
  u16* Ep = smem + w * (32 * 72);
#pragma unroll
  for (int nt = 0; nt < 2; nt++) {
    const floatx16& o = nt ? o1 : o0;
#pragma unroll
    for (int r = 0; r < 16; r++) {
      const int rl = (r & 3) + 8 * (r >> 2) + 4 * hi;
      Ep[rl * 72 + nt * 32 + lq] = f2b(o[r] * invr[r]);
    }
  }
  __syncthreads();
  {
    const int row = tid >> 1, half = tid & 1;   // 128 rows x 2 halves of 64B
    const u16* src = smem + (row >> 5) * (32 * 72) + (row & 31) * 72 + half * 32;
    const int t = q0 + row;
    const int b = bh / H_, h = bh % H_;
    const size_t yi = ((size_t)b * T_ + t) * C_ + (size_t)h * 64 + half * 32;
#pragma unroll
    for (int i = 0; i < 4; i++)
      *reinterpret_cast<uint4*>(Yg + yi + i * 8) =
          *reinterpret_cast<const uint4*>(src + i * 8);
  }
}

// ---------------------------------------------------------------------------
// Out projection — round-15 proven config: BK=32, 4 blocks/CU.
// ---------------------------------------------------------------------------
#define OUT_SBUF 6144    // u16 per buffer (12KB)

__global__ __launch_bounds__(256, 4) void out_mfma(
    const u16* __restrict__ Xb, const u16* __restrict__ Wfb, float* __restrict__ Og)
{
  __shared__ __align__(16) u16 smem[17408];   // buffers at 0/6144; fp32 Ep 34816B

  const int id = blockIdx.x;
  const int xcd = id & 7;
  const int s = id >> 3;              // 0..95
  const int m0 = (xcd * 16 + s / 6) * 128;
  const int n0 = (s % 6) * 64;

  const int tid = threadIdx.x;
  const int w = tid >> 6;
  const int lane = tid & 63;
  const int quad = lane >> 4;
  const int c = lane & 15;

  floatx4 acc[2][4];
#pragma unroll
  for (int i = 0; i < 2; i++)
#pragma unroll
    for (int j = 0; j < 4; j++) acc[i][j] = (floatx4){0.f, 0.f, 0.f, 0.f};

  const int lrow = lane >> 2;        // row within a 16-row chunk
  const int lcol = (lane & 3) * 8;   // 8-col offset within 32 cols

  auto STAGE = [&](int bb, int k0) {
    u16* base = smem + bb * OUT_SBUF;
#pragma unroll
    for (int n = 0; n < 2; n++) {
      const int ch = w * 2 + n;
      gl_lds16(Xb + (size_t)(m0 + ch * 16 + lrow) * C_ + k0 + lcol, base + ch * 512);
    }
    gl_lds16(Wfb + (size_t)(n0 + w * 16 + lrow) * C_ + k0 + lcol,
             base + 4096 + w * 512);
  };

  STAGE(0, 0);
  __syncthreads();

  for (int i = 0; i < 12; i++) {
    const int bb = i & 1;
    if (i < 11) STAGE(bb ^ 1, (i + 1) * 32);

    const u16* As = smem + bb * OUT_SBUF;
    const u16* Bs = As + 4096;
    __builtin_amdgcn_s_setprio(1);
    short8 af[2], bf[4];
#pragma unroll
    for (int mi = 0; mi < 2; mi++)
      af[mi] = *reinterpret_cast<const short8*>(
          As + (w * 32 + mi * 16 + c) * 32 + quad * 8);
#pragma unroll
    for (int ni = 0; ni < 4; ni++)
      bf[ni] = *reinterpret_cast<const short8*>(
          Bs + (ni * 16 + c) * 32 + quad * 8);
#pragma unroll
    for (int mi = 0; mi < 2; mi++)
#pragma unroll
      for (int ni = 0; ni < 4; ni++)
        acc[mi][ni] = __builtin_amdgcn_mfma_f32_16x16x32_bf16(af[mi], bf[ni], acc[mi][ni], 0, 0, 0);
    __builtin_amdgcn_s_setprio(0);
    if (i < 11) __syncthreads();
  }

  __syncthreads();
  float* Ep = reinterpret_cast<float*>(smem) + w * (32 * 68);
#pragma unroll
  for (int mi = 0; mi < 2; mi++)
#pragma unroll
    for (int ni = 0; ni < 4; ni++) {
      int rw = mi * 16 + quad * 4;
      int col = ni * 16 + c;
#pragma unroll
      for (int r = 0; r < 4; r++)
        Ep[(rw + r) * 68 + col] = acc[mi][ni][r];
    }
  __syncthreads();
  {
    int rw2 = lane >> 1, half = lane & 1;
    const float* src = Ep + rw2 * 68 + half * 32;
    float* dst = Og + (size_t)(m0 + w * 32 + rw2) * C_ + n0 + half * 32;
#pragma unroll
    for (int i = 0; i < 8; i++)
      *reinterpret_cast<float4*>(dst + i * 4) =
          *reinterpret_cast<const float4*>(src + i * 4);
  }
}

// ---------------------------------------------------------------------------
extern "C" void kernel_launch(void* const* d_in, const int* in_sizes, int n_in,
                              void* d_out, int out_size, void* d_ws, size_t ws_size,
                              hipStream_t stream) {
  (void)in_sizes; (void)n_in; (void)out_size; (void)ws_size;
  const float* x    = (const float*)d_in[0];
  const float* Wq   = (const float*)d_in[1];
  const float* Wk   = (const float*)d_in[2];
  const float* Wv   = (const float*)d_in[3];
  const float* Wo   = (const float*)d_in[4];
  const float* cosb = (const float*)d_in[5];
  const float* sinb = (const float*)d_in[6];

  const size_t MC = (size_t)M_ * C_;    // 6291456
  u16* ws = (u16*)d_ws;
  u16* Q   = ws;                        // [B][H][T][D] bf16 (pre-scaled)
  u16* K   = Q + MC;
  u16* Vt  = K + MC;                    // [B][H][D][T] bf16
  u16* Y   = Vt + MC;                   // attn out [B*T][C] bf16; doubles as Xb
  u16* Xb  = Y;                         // bf16 X (consumed by qkv before attn writes Y)
  u16* Wb  = Y + MC;                    // 4 x 147456 bf16 weights
  u16* Wqb = Wb;
  u16* Wkb = Wb + 147456;
  u16* Wvb = Wb + 2 * 147456;
  u16* Wob = Wb + 3 * 147456;
  float* out = (float*)d_out;

  prep_bf16<<<3360, 256, 0, stream>>>(x, Wq, Wk, Wv, Wo, Xb, Wqb, Wkb, Wvb, Wob);

  qkv_fused<<<768, 256, 0, stream>>>(Xb, Wqb, Wkb, Wvb, cosb, sinb, Q, K, Vt);

  attn_mfma<<<768, 256, 0, stream>>>(Q, K, Vt, Y);

  out_mfma<<<768, 256, 0, stream>>>(Y, Wob, out);
}

// Round 18
// 192.156 us; speedup vs baseline: 1.0622x; 1.0329x over previous
//
#include <hip/hip_runtime.h>
#include <hip/hip_bf16.h>
#include <stdint.h>

#define B_ 8
#define T_ 2048
#define C_ 384
#define H_ 6
#define D_ 64
#define M_ (B_*T_)   // 16384

typedef unsigned short u16;
typedef unsigned int u32;
typedef __attribute__((ext_vector_type(8))) short short8;
typedef __attribute__((ext_vector_type(4))) float floatx4;
typedef __attribute__((ext_vector_type(16))) float floatx16;

// softmax scale folded into stored Q: 0.125 * log2(e)
#define QSCALE 0.18033688011112042f

__device__ __forceinline__ u16 f2b(float f) {
  union { float f; unsigned u; } x; x.f = f;
  unsigned r = x.u + 0x7fffu + ((x.u >> 16) & 1u);  // round-nearest-even
  return (u16)(r >> 16);
}
__device__ __forceinline__ u32 pack_bf16(float a, float b) {
  union { __hip_bfloat162 h; u32 u; } x;
  x.h = __float22bfloat162_rn(float2{a, b});
  return x.u;
}
__device__ __forceinline__ uint4 pack8(const float4& lo, const float4& hi) {
  uint4 r;
  r.x = pack_bf16(lo.x, lo.y); r.y = pack_bf16(lo.z, lo.w);
  r.z = pack_bf16(hi.x, hi.y); r.w = pack_bf16(hi.z, hi.w);
  return r;
}

// v_permlane32_swap_b32: swaps a.hi(32 lanes) <-> b.lo(32 lanes).
__device__ __forceinline__ void plswap(u32& a, u32& b) {
  asm("v_permlane32_swap_b32 %0, %1" : "+v"(a), "+v"(b));
}

// bare v_exp_f32 — no libm range/denormal fixup (inputs bounded: |s|<=11.6)
__device__ __forceinline__ float fexp2(float x) {
#if __has_builtin(__builtin_amdgcn_exp2f)
  return __builtin_amdgcn_exp2f(x);
#else
  float r; asm("v_exp_f32 %0, %1" : "=v"(r) : "v"(x)); return r;
#endif
}

// packed f32x2 -> bf16x2 in ONE instruction (dst.lo = bf16(a), dst.hi = bf16(b))
__device__ __forceinline__ u32 cvtpk(float a, float b) {
  u32 r; asm("v_cvt_pk_bf16_f32 %0, %1, %2" : "=v"(r) : "v"(a), "v"(b)); return r;
}

// async global->LDS, 16B per lane.
__device__ __forceinline__ void gl_lds16(const u16* g, u16* l) {
#if __has_builtin(__builtin_amdgcn_global_load_lds)
  __builtin_amdgcn_global_load_lds(
      (const __attribute__((address_space(1))) unsigned int*)g,
      (__attribute__((address_space(3))) unsigned int*)l,
      16, 0, 0);
#else
  *reinterpret_cast<uint4*>(l + (threadIdx.x & 63) * 8) =
      *reinterpret_cast<const uint4*>(g);
#endif
}

// raw workgroup barrier WITHOUT waitcnt drain (counted-vmcnt pipelining).
// sched_barrier(0) + "memory" clobbers fence compiler reordering (rule #18).
__device__ __forceinline__ void rawbar() {
  __builtin_amdgcn_sched_barrier(0);
  asm volatile("" ::: "memory");
  __builtin_amdgcn_s_barrier();
  asm volatile("" ::: "memory");
  __builtin_amdgcn_sched_barrier(0);
}

// ---------------------------------------------------------------------------
// prep: one-time fp32 -> bf16 conversion of X and the four weight matrices.
// ---------------------------------------------------------------------------
__global__ __launch_bounds__(256) void prep_bf16(
    const float* __restrict__ x,
    const float* __restrict__ wq, const float* __restrict__ wk,
    const float* __restrict__ wv, const float* __restrict__ wo,
    u16* __restrict__ xb,
    u16* __restrict__ wqb, u16* __restrict__ wkb,
    u16* __restrict__ wvb, u16* __restrict__ wob)
{
  const int c = blockIdx.x * 256 + threadIdx.x;
  const float* src;
  u16* dst;
  int off;
  if (c < 786432) {                 // X: 6291456 / 8
    src = x; dst = xb; off = c;
  } else {
    int t = c - 786432;             // W: 147456 / 8 = 18432 chunks each
    int wsel = t / 18432;
    off = t - wsel * 18432;
    src = (wsel == 0) ? wq : (wsel == 1) ? wk : (wsel == 2) ? wv : wo;
    dst = (wsel == 0) ? wqb : (wsel == 1) ? wkb : (wsel == 2) ? wvb : wob;
  }
  const float4* p = reinterpret_cast<const float4*>(src + (size_t)off * 8);
  float4 lo = p[0], hi = p[1];
  *reinterpret_cast<uint4*>(dst + (size_t)off * 8) = pack8(lo, hi);
}

// ---------------------------------------------------------------------------
// Fused QKV projection — round 18: BK=32 dbuf + COUNTED-vmcnt raw barriers.
// Per step: vmcnt(5) [STAGE(i) landed; STAGE(i+1)'s 5 stay in flight] ->
// barrier -> compute(i) -> barrier -> issue STAGE(i+2) into b[i&1].
// Loads get TWO k-steps of flight; vmcnt never drains to 0 in the loop.
// Writer-after-reader safe: STAGE issued only after the post-compute barrier.
// ---------------------------------------------------------------------------
#define QKV_SBUF 10240   // u16 per buffer (20KB)

__global__ __launch_bounds__(256, 3) void qkv_fused(
    const u16* __restrict__ Xb,
    const u16* __restrict__ Wqb, const u16* __restrict__ Wkb, const u16* __restrict__ Wvb,
    const float* __restrict__ cosb, const float* __restrict__ sinb,
    u16* __restrict__ Qo, u16* __restrict__ Ko, u16* __restrict__ Vto)
{
  __shared__ __align__(16) u16 smem[2 * QKV_SBUF];   // 40 KB (epilogue: 18KB)

  // XCD remap: 768 wgs = 8 xcds x (16 m-blocks x 6 heads)
  const int id = blockIdx.x;
  const int xcd = id & 7;
  const int s = id >> 3;              // 0..95
  const int mb = xcd * 16 + s / 6;    // 0..127
  const int hh = s % 6;
  const int m0 = mb * 128;
  const int n0 = hh * 64;

  const int tid = threadIdx.x;
  const int w = tid >> 6;
  const int lane = tid & 63;
  const int quad = lane >> 4;
  const int c = lane & 15;

  const u16* Wz[3] = {Wqb, Wkb, Wvb};

  floatx4 acc[3][2][4];
#pragma unroll
  for (int z = 0; z < 3; z++)
#pragma unroll
    for (int i = 0; i < 2; i++)
#pragma unroll
      for (int j = 0; j < 4; j++) acc[z][i][j] = (floatx4){0.f, 0.f, 0.f, 0.f};

  const int lrow = lane >> 2;        // row within a 16-row chunk
  const int lcol = (lane & 3) * 8;   // 8-col (16B) offset within 32 cols

  // stage k-step k0 into buffer bb: 5 gl_lds16 per lane (2 A + 3 B)
  auto STAGE = [&](int bb, int k0) {
    u16* base = smem + bb * QKV_SBUF;
#pragma unroll
    for (int n = 0; n < 2; n++) {
      const int ch = w * 2 + n;
      gl_lds16(Xb + (size_t)(m0 + ch * 16 + lrow) * C_ + k0 + lcol, base + ch * 512);
    }
#pragma unroll
    for (int n = 0; n < 3; n++) {
      const int idx = w * 3 + n;       // 0..11
      const int z = idx >> 2;
      const int chz = idx & 3;
      gl_lds16(Wz[z] + (size_t)(n0 + chz * 16 + lrow) * C_ + k0 + lcol,
               base + 4096 + z * 2048 + chz * 512);
    }
  };

  STAGE(0, 0);       // 5 outstanding
  STAGE(1, 32);      // 10 outstanding

  for (int i = 0; i < 12; i++) {
    // wait until STAGE(i) has landed; STAGE(i+1)'s 5 loads remain in flight
    if (i < 11) asm volatile("s_waitcnt vmcnt(5)" ::: "memory");
    else        asm volatile("s_waitcnt vmcnt(0)" ::: "memory");
    rawbar();    // all waves' STAGE(i) data visible in LDS

    const u16* As = smem + (i & 1) * QKV_SBUF;
    const u16* Bs0 = As + 4096;
    __builtin_amdgcn_s_setprio(1);
    short8 af2[2];
#pragma unroll
    for (int mi = 0; mi < 2; mi++)
      af2[mi] = *reinterpret_cast<const short8*>(
          As + (w * 32 + mi * 16 + c) * 32 + quad * 8);
#pragma unroll
    for (int z = 0; z < 3; z++) {
#pragma unroll
      for (int ni = 0; ni < 4; ni++) {
        short8 bf = *reinterpret_cast<const short8*>(
            Bs0 + z * 2048 + (ni * 16 + c) * 32 + quad * 8);
#pragma unroll
        for (int mi = 0; mi < 2; mi++)
          acc[z][mi][ni] = __builtin_amdgcn_mfma_f32_16x16x32_bf16(af2[mi], bf, acc[z][mi][ni], 0, 0, 0);
      }
    }
    __builtin_amdgcn_s_setprio(0);

    rawbar();    // all waves done reading b[i&1]
    if (i + 2 < 12) STAGE(i & 1, (i + 2) * 32);   // overwrite just-read buffer
  }

  const int bb2 = m0 >> 11;
  const int tbase = m0 & (T_ - 1);

  // ---- V: register scatter to Vt[B][H][D][T] ----
  {
    const size_t vbase = ((size_t)(bb2 * H_ + hh)) * D_ * T_;
#pragma unroll
    for (int mi = 0; mi < 2; mi++) {
      int t = tbase + w * 32 + mi * 16 + quad * 4;
#pragma unroll
      for (int ni = 0; ni < 4; ni++) {
        int d = ni * 16 + c;
        ushort4 pk;
        pk.x = f2b(acc[2][mi][ni][0]); pk.y = f2b(acc[2][mi][ni][1]);
        pk.z = f2b(acc[2][mi][ni][2]); pk.w = f2b(acc[2][mi][ni][3]);
        *reinterpret_cast<ushort4*>(Vto + vbase + (size_t)d * T_ + t) = pk;
      }
    }
  }

  // ---- Q then K: lane-parallel RMS + RoPE, LDS transpose store ----
  u16* Ep = smem;
#pragma unroll
  for (int zz = 0; zz < 2; zz++) {
    __syncthreads();
#pragma unroll
    for (int mi = 0; mi < 2; mi++) {
      float ssr[4];
#pragma unroll
      for (int r = 0; r < 4; r++) {
        float s0 = acc[zz][mi][0][r], s1 = acc[zz][mi][1][r];
        float s2 = acc[zz][mi][2][r], s3 = acc[zz][mi][3][r];
        ssr[r] = s0 * s0 + s1 * s1 + s2 * s2 + s3 * s3;
      }
#pragma unroll
      for (int off = 1; off < 16; off <<= 1)
#pragma unroll
        for (int r = 0; r < 4; r++) ssr[r] += __shfl_xor(ssr[r], off, 64);
      int rowb = w * 32 + mi * 16 + quad * 4;
#pragma unroll
      for (int r = 0; r < 4; r++) {
        float scl = rsqrtf(ssr[r] * (1.0f / 64.0f) + 1e-5f);
        if (zz == 0) scl *= QSCALE;     // fold softmax scale into Q
        int t = tbase + rowb + r;
#pragma unroll
        for (int h2 = 0; h2 < 2; h2++) {
          float cs = cosb[t * 32 + h2 * 16 + c];
          float sn = sinb[t * 32 + h2 * 16 + c];
          float x1 = acc[zz][mi][h2][r];
          float x2 = acc[zz][mi][h2 + 2][r];
          Ep[(rowb + r) * 72 + h2 * 16 + c]       = f2b((x1 * cs + x2 * sn) * scl);
          Ep[(rowb + r) * 72 + (h2 + 2) * 16 + c] = f2b((x2 * cs - x1 * sn) * scl);
        }
      }
    }
    __syncthreads();
    {
      int row = tid >> 1, half = tid & 1;
      int t = tbase + row;
      u16* Og = (zz == 0) ? Qo : Ko;
      u16* dst = Og + (((size_t)(bb2 * H_ + hh)) * T_ + t) * D_ + half * 32;
#pragma unroll
      for (int i = 0; i < 4; i++)
        *reinterpret_cast<uint4*>(dst + i * 8) =
            *reinterpret_cast<const uint4*>(Ep + row * 72 + half * 32 + i * 8);
    }
  }
}

// ---------------------------------------------------------------------------
// MFMA flash attention — round-14/15 proven config (63.3-64.9us): stride-72
// layout, identity slots, l ones-MFMA interleaved into PV, setprio.
// UNTOUCHED this round.
// ---------------------------------------------------------------------------
#define ATT_LDA 72        // u16 row stride (144 B, 16B-aligned, bank-rotating)
#define ATT_VOFF 4608     // 64 rows * 72
#define ATT_BUF 9216      // K+V plane per buffer (u16)

__global__ __launch_bounds__(256, 3) void attn_mfma(
    const u16* __restrict__ Qg, const u16* __restrict__ Kg,
    const u16* __restrict__ Vtg, u16* __restrict__ Yg)
{
  __shared__ __align__(16) u16 smem[2 * ATT_BUF];   // 36864 B

  const int tid = threadIdx.x;
  const int w = tid >> 6;
  const int lane = tid & 63;
  const int hi = lane >> 5;
  const int lq = lane & 31;

  // XCD remap: 768 wgs = 8 xcds x (6 bh x 16 q-blocks)
  const int id = blockIdx.x;
  const int xcd = id & 7;
  const int slot = id >> 3;              // 0..95
  const int bh = xcd * 6 + (slot >> 4);  // 0..47
  const int q0 = (slot & 15) * 128;

  const size_t baseQK = (size_t)bh * T_ * D_;
  const size_t baseV  = (size_t)bh * D_ * T_;

  // Q fragments (B-operand): lane holds Q[q0+w*32+lq][ds*16 + hi*8 + j]
  short8 qf[4];
  {
    const u16* qp = Qg + baseQK + (size_t)(q0 + w * 32 + lq) * D_ + hi * 8;
#pragma unroll
    for (int d = 0; d < 4; d++)
      qf[d] = *reinterpret_cast<const short8*>(qp + d * 16);
  }

  floatx16 z16;
#pragma unroll
  for (int i = 0; i < 16; i++) z16[i] = 0.f;
  short8 vones;
#pragma unroll
  for (int i = 0; i < 8; i++) vones[i] = (short)0x3F80;

  // staging: 256 threads cover 64 rows x 2 x 16B chunks; identity slots
  const int sr = tid >> 2;
  const int sch = tid & 3;
  const int ko0 = sr * ATT_LDA + sch * 8;
  const int ko1 = sr * ATT_LDA + (sch + 4) * 8;
  const int vo0 = ATT_VOFF + ko0;
  const int vo1 = ATT_VOFF + ko1;
  const u16* kga = Kg + baseQK + (size_t)sr * D_ + sch * 8;
  const u16* vga = Vtg + baseV + (size_t)sr * T_ + sch * 8;

  // prologue: tile 0 -> regs -> buf0; then prefetch tile 1 into regs
  uint4 ka = *reinterpret_cast<const uint4*>(kga);
  uint4 kb = *reinterpret_cast<const uint4*>(kga + 32);
  uint4 va = *reinterpret_cast<const uint4*>(vga);
  uint4 vb = *reinterpret_cast<const uint4*>(vga + 32);
  *reinterpret_cast<uint4*>(smem + ko0) = ka;
  *reinterpret_cast<uint4*>(smem + ko1) = kb;
  *reinterpret_cast<uint4*>(smem + vo0) = va;
  *reinterpret_cast<uint4*>(smem + vo1) = vb;
  const u16* kload = kga + (size_t)64 * D_;
  const u16* vload = vga + 64;
  ka = *reinterpret_cast<const uint4*>(kload);
  kb = *reinterpret_cast<const uint4*>(kload + 32);
  va = *reinterpret_cast<const uint4*>(vload);
  vb = *reinterpret_cast<const uint4*>(vload + 32);
  kload += (size_t)64 * D_;
  vload += 64;

  floatx16 o0 = z16, o1 = z16;
  floatx16 l_acc = z16;

  // hoisted thread-invariant LDS read offsets (identity slots)
  int koff[2][4], voff[2][4];
#pragma unroll
  for (int ds = 0; ds < 4; ds++) {
    const int xr = ds * 2 + hi;
    koff[0][ds] = lq * ATT_LDA + xr * 8;
    koff[1][ds] = (32 + lq) * ATT_LDA + xr * 8;
    voff[0][ds] = ATT_VOFF + lq * ATT_LDA + xr * 8;
    voff[1][ds] = ATT_VOFF + (32 + lq) * ATT_LDA + xr * 8;
  }

  for (int kt = 0; kt < 32; kt++) {
    __syncthreads();   // buf[kt&1] fully written; buf[(kt+1)&1] fully read

    // write prefetched tile kt+1 into the other buffer; issue loads kt+2
    if (kt < 31) {
      u16* wb = smem + ((kt + 1) & 1) * ATT_BUF;
      *reinterpret_cast<uint4*>(wb + ko0) = ka;
      *reinterpret_cast<uint4*>(wb + ko1) = kb;
      *reinterpret_cast<uint4*>(wb + vo0) = va;
      *reinterpret_cast<uint4*>(wb + vo1) = vb;
      if (kt < 30) {
        ka = *reinterpret_cast<const uint4*>(kload);
        kb = *reinterpret_cast<const uint4*>(kload + 32);
        va = *reinterpret_cast<const uint4*>(vload);
        vb = *reinterpret_cast<const uint4*>(vload + 32);
        kload += (size_t)64 * D_;
        vload += 64;
      }
    }

    const u16* Ksb = smem + (kt & 1) * ATT_BUF;

    // ---- QK^T (swapped): st = K * Q^T, col = q (lane-local), rows = t ----
    floatx16 st0, st1;
    __builtin_amdgcn_s_setprio(1);
    {
      short8 kf0 = *reinterpret_cast<const short8*>(Ksb + koff[0][0]);
      short8 kf1 = *reinterpret_cast<const short8*>(Ksb + koff[1][0]);
      st0 = __builtin_amdgcn_mfma_f32_32x32x16_bf16(kf0, qf[0], z16, 0, 0, 0);
      st1 = __builtin_amdgcn_mfma_f32_32x32x16_bf16(kf1, qf[0], z16, 0, 0, 0);
    }
#pragma unroll
    for (int ds = 1; ds < 4; ds++) {
      short8 kf0 = *reinterpret_cast<const short8*>(Ksb + koff[0][ds]);
      short8 kf1 = *reinterpret_cast<const short8*>(Ksb + koff[1][ds]);
      st0 = __builtin_amdgcn_mfma_f32_32x32x16_bf16(kf0, qf[ds], st0, 0, 0, 0);
      st1 = __builtin_amdgcn_mfma_f32_32x32x16_bf16(kf1, qf[ds], st1, 0, 0, 0);
    }
    __builtin_amdgcn_s_setprio(0);

    // ---- softmax: p = exp2(s), bare v_exp_f32 ----
#pragma unroll
    for (int r = 0; r < 16; r++) {
      st0[r] = fexp2(st0[r]);
      st1[r] = fexp2(st1[r]);
    }

    // ---- P -> bf16 A-fragments: 16 v_cvt_pk + 8 permlane32_swap ----
    short8 pa[4];
#pragma unroll
    for (int ks = 0; ks < 4; ks++) {
      const floatx16& s = (ks < 2) ? st0 : st1;
      const int rb = (ks & 1) * 8;
      u32 ca = cvtpk(s[rb + 0], s[rb + 1]);
      u32 cb = cvtpk(s[rb + 2], s[rb + 3]);
      u32 cc = cvtpk(s[rb + 4], s[rb + 5]);
      u32 cd = cvtpk(s[rb + 6], s[rb + 7]);
      plswap(ca, cc);
      plswap(cb, cd);
      short8 pf;
      u32* pfu = reinterpret_cast<u32*>(&pf);
      pfu[0] = ca; pfu[1] = cb; pfu[2] = cc; pfu[3] = cd;
      pa[ks] = pf;
    }

    // ---- PV + l row-sums: 3 independent chains (o0/o1/l) interleaved ----
    __builtin_amdgcn_s_setprio(1);
#pragma unroll
    for (int ks = 0; ks < 4; ks++) {
      short8 vf0 = *reinterpret_cast<const short8*>(Ksb + voff[0][ks]);
      short8 vf1 = *reinterpret_cast<const short8*>(Ksb + voff[1][ks]);
      o0 = __builtin_amdgcn_mfma_f32_32x32x16_bf16(pa[ks], vf0, o0, 0, 0, 0);
      o1 = __builtin_amdgcn_mfma_f32_32x32x16_bf16(pa[ks], vf1, o1, 0, 0, 0);
      l_acc = __builtin_amdgcn_mfma_f32_32x32x16_bf16(pa[ks], vones, l_acc, 0, 0, 0);
    }
    __builtin_amdgcn_s_setprio(0);
  }

  // normalization: l_acc[r] holds l for exactly the q-row o[r] holds
  float invr[16];
#pragma unroll
  for (int r = 0; r < 16; r++) invr[r] = __builtin_amdgcn_rcpf(l_acc[r]);

  __syncthreads();   // done with K/V buffers; reuse smem for epilogue
  u16* Ep = smem + w * (32 * 72);
#pragma unroll
  for (int nt = 0; nt < 2; nt++) {
    const floatx16& o = nt ? o1 : o0;
#pragma unroll
    for (int r = 0; r < 16; r++) {
      const int rl = (r & 3) + 8 * (r >> 2) + 4 * hi;
      Ep[rl * 72 + nt * 32 + lq] = f2b(o[r] * invr[r]);
    }
  }
  __syncthreads();
  {
    const int row = tid >> 1, half = tid & 1;   // 128 rows x 2 halves of 64B
    const u16* src = smem + (row >> 5) * (32 * 72) + (row & 31) * 72 + half * 32;
    const int t = q0 + row;
    const int b = bh / H_, h = bh % H_;
    const size_t yi = ((size_t)b * T_ + t) * C_ + (size_t)h * 64 + half * 32;
#pragma unroll
    for (int i = 0; i < 4; i++)
      *reinterpret_cast<uint4*>(Yg + yi + i * 8) =
          *reinterpret_cast<const uint4*>(src + i * 8);
  }
}

// ---------------------------------------------------------------------------
// Out projection — round 18: BK=32 dbuf + counted-vmcnt raw barriers
// (3 gl_lds16 per lane per STAGE -> vmcnt(3)).
// ---------------------------------------------------------------------------
#define OUT_SBUF 6144    // u16 per buffer (12KB)

__global__ __launch_bounds__(256, 4) void out_mfma(
    const u16* __restrict__ Xb, const u16* __restrict__ Wfb, float* __restrict__ Og)
{
  __shared__ __align__(16) u16 smem[17408];   // buffers at 0/6144; fp32 Ep 34816B

  const int id = blockIdx.x;
  const int xcd = id & 7;
  const int s = id >> 3;              // 0..95
  const int m0 = (xcd * 16 + s / 6) * 128;
  const int n0 = (s % 6) * 64;

  const int tid = threadIdx.x;
  const int w = tid >> 6;
  const int lane = tid & 63;
  const int quad = lane >> 4;
  const int c = lane & 15;

  floatx4 acc[2][4];
#pragma unroll
  for (int i = 0; i < 2; i++)
#pragma unroll
    for (int j = 0; j < 4; j++) acc[i][j] = (floatx4){0.f, 0.f, 0.f, 0.f};

  const int lrow = lane >> 2;        // row within a 16-row chunk
  const int lcol = (lane & 3) * 8;   // 8-col offset within 32 cols

  auto STAGE = [&](int bb, int k0) {
    u16* base = smem + bb * OUT_SBUF;
#pragma unroll
    for (int n = 0; n < 2; n++) {
      const int ch = w * 2 + n;
      gl_lds16(Xb + (size_t)(m0 + ch * 16 + lrow) * C_ + k0 + lcol, base + ch * 512);
    }
    gl_lds16(Wfb + (size_t)(n0 + w * 16 + lrow) * C_ + k0 + lcol,
             base + 4096 + w * 512);
  };

  STAGE(0, 0);       // 3 outstanding
  STAGE(1, 32);      // 6 outstanding

  for (int i = 0; i < 12; i++) {
    if (i < 11) asm volatile("s_waitcnt vmcnt(3)" ::: "memory");
    else        asm volatile("s_waitcnt vmcnt(0)" ::: "memory");
    rawbar();

    const u16* As = smem + (i & 1) * OUT_SBUF;
    const u16* Bs = As + 4096;
    __builtin_amdgcn_s_setprio(1);
    short8 af[2], bf[4];
#pragma unroll
    for (int mi = 0; mi < 2; mi++)
      af[mi] = *reinterpret_cast<const short8*>(
          As + (w * 32 + mi * 16 + c) * 32 + quad * 8);
#pragma unroll
    for (int ni = 0; ni < 4; ni++)
      bf[ni] = *reinterpret_cast<const short8*>(
          Bs + (ni * 16 + c) * 32 + quad * 8);
#pragma unroll
    for (int mi = 0; mi < 2; mi++)
#pragma unroll
      for (int ni = 0; ni < 4; ni++)
        acc[mi][ni] = __builtin_amdgcn_mfma_f32_16x16x32_bf16(af[mi], bf[ni], acc[mi][ni], 0, 0, 0);
    __builtin_amdgcn_s_setprio(0);

    rawbar();
    if (i + 2 < 12) STAGE(i & 1, (i + 2) * 32);
  }

  __syncthreads();
  float* Ep = reinterpret_cast<float*>(smem) + w * (32 * 68);
#pragma unroll
  for (int mi = 0; mi < 2; mi++)
#pragma unroll
    for (int ni = 0; ni < 4; ni++) {
      int rw = mi * 16 + quad * 4;
      int col = ni * 16 + c;
#pragma unroll
      for (int r = 0; r < 4; r++)
        Ep[(rw + r) * 68 + col] = acc[mi][ni][r];
    }
  __syncthreads();
  {
    int rw2 = lane >> 1, half = lane & 1;
    const float* src = Ep + rw2 * 68 + half * 32;
    float* dst = Og + (size_t)(m0 + w * 32 + rw2) * C_ + n0 + half * 32;
#pragma unroll
    for (int i = 0; i < 8; i++)
      *reinterpret_cast<float4*>(dst + i * 4) =
          *reinterpret_cast<const float4*>(src + i * 4);
  }
}

// ---------------------------------------------------------------------------
extern "C" void kernel_launch(void* const* d_in, const int* in_sizes, int n_in,
                              void* d_out, int out_size, void* d_ws, size_t ws_size,
                              hipStream_t stream) {
  (void)in_sizes; (void)n_in; (void)out_size; (void)ws_size;
  const float* x    = (const float*)d_in[0];
  const float* Wq   = (const float*)d_in[1];
  const float* Wk   = (const float*)d_in[2];
  const float* Wv   = (const float*)d_in[3];
  const float* Wo   = (const float*)d_in[4];
  const float* cosb = (const float*)d_in[5];
  const float* sinb = (const float*)d_in[6];

  const size_t MC = (size_t)M_ * C_;    // 6291456
  u16* ws = (u16*)d_ws;
  u16* Q   = ws;                        // [B][H][T][D] bf16 (pre-scaled)
  u16* K   = Q + MC;
  u16* Vt  = K + MC;                    // [B][H][D][T] bf16
  u16* Y   = Vt + MC;                   // attn out [B*T][C] bf16; doubles as Xb
  u16* Xb  = Y;                         // bf16 X (consumed by qkv before attn writes Y)
  u16* Wb  = Y + MC;                    // 4 x 147456 bf16 weights
  u16* Wqb = Wb;
  u16* Wkb = Wb + 147456;
  u16* Wvb = Wb + 2 * 147456;
  u16* Wob = Wb + 3 * 147456;
  float* out = (float*)d_out;

  prep_bf16<<<3360, 256, 0, stream>>>(x, Wq, Wk, Wv, Wo, Xb, Wqb, Wkb, Wvb, Wob);

  qkv_fused<<<768, 256, 0, stream>>>(Xb, Wqb, Wkb, Wvb, cosb, sinb, Q, K, Vt);

  attn_mfma<<<768, 256, 0, stream>>>(Q, K, Vt, Y);

  out_mfma<<<768, 256, 0, stream>>>(Y, Wob, out);
}

// Round 19
// 188.962 us; speedup vs baseline: 1.0802x; 1.0169x over previous
//
#include <hip/hip_runtime.h>
#include <hip/hip_bf16.h>
#include <stdint.h>

#define B_ 8
#define T_ 2048
#define C_ 384
#define H_ 6
#define D_ 64
#define M_ (B_*T_)   // 16384

typedef unsigned short u16;
typedef unsigned int u32;
typedef __attribute__((ext_vector_type(8))) short short8;
typedef __attribute__((ext_vector_type(4))) float floatx4;
typedef __attribute__((ext_vector_type(16))) float floatx16;

// softmax scale folded into stored Q: 0.125 * log2(e)
#define QSCALE 0.18033688011112042f

__device__ __forceinline__ u16 f2b(float f) {
  union { float f; unsigned u; } x; x.f = f;
  unsigned r = x.u + 0x7fffu + ((x.u >> 16) & 1u);  // round-nearest-even
  return (u16)(r >> 16);
}
__device__ __forceinline__ u32 pack_bf16(float a, float b) {
  union { __hip_bfloat162 h; u32 u; } x;
  x.h = __float22bfloat162_rn(float2{a, b});
  return x.u;
}
__device__ __forceinline__ uint4 pack8(const float4& lo, const float4& hi) {
  uint4 r;
  r.x = pack_bf16(lo.x, lo.y); r.y = pack_bf16(lo.z, lo.w);
  r.z = pack_bf16(hi.x, hi.y); r.w = pack_bf16(hi.z, hi.w);
  return r;
}

// v_permlane32_swap_b32: swaps a.hi(32 lanes) <-> b.lo(32 lanes).
__device__ __forceinline__ void plswap(u32& a, u32& b) {
  asm("v_permlane32_swap_b32 %0, %1" : "+v"(a), "+v"(b));
}

// bare v_exp_f32 — no libm range/denormal fixup (inputs bounded: |s|<=11.6)
__device__ __forceinline__ float fexp2(float x) {
#if __has_builtin(__builtin_amdgcn_exp2f)
  return __builtin_amdgcn_exp2f(x);
#else
  float r; asm("v_exp_f32 %0, %1" : "=v"(r) : "v"(x)); return r;
#endif
}

// packed f32x2 -> bf16x2 in ONE instruction (dst.lo = bf16(a), dst.hi = bf16(b))
__device__ __forceinline__ u32 cvtpk(float a, float b) {
  u32 r; asm("v_cvt_pk_bf16_f32 %0, %1, %2" : "=v"(r) : "v"(a), "v"(b)); return r;
}

// async global->LDS, 16B per lane.
__device__ __forceinline__ void gl_lds16(const u16* g, u16* l) {
#if __has_builtin(__builtin_amdgcn_global_load_lds)
  __builtin_amdgcn_global_load_lds(
      (const __attribute__((address_space(1))) unsigned int*)g,
      (__attribute__((address_space(3))) unsigned int*)l,
      16, 0, 0);
#else
  *reinterpret_cast<uint4*>(l + (threadIdx.x & 63) * 8) =
      *reinterpret_cast<const uint4*>(g);
#endif
}

// raw workgroup barrier WITHOUT waitcnt drain (counted-vmcnt pipelining).
__device__ __forceinline__ void rawbar() {
  __builtin_amdgcn_sched_barrier(0);
  asm volatile("" ::: "memory");
  __builtin_amdgcn_s_barrier();
  asm volatile("" ::: "memory");
  __builtin_amdgcn_sched_barrier(0);
}

// ---------------------------------------------------------------------------
// prep: one-time fp32 -> bf16 conversion of the four weight matrices ONLY
// (X conversion folded into qkv's A-staging).  73728 chunks -> 288 blocks.
// ---------------------------------------------------------------------------
__global__ __launch_bounds__(256) void prep_w(
    const float* __restrict__ wq, const float* __restrict__ wk,
    const float* __restrict__ wv, const float* __restrict__ wo,
    u16* __restrict__ wqb, u16* __restrict__ wkb,
    u16* __restrict__ wvb, u16* __restrict__ wob)
{
  const int c = blockIdx.x * 256 + threadIdx.x;   // 0..73727
  const int wsel = c / 18432;
  const int off = c - wsel * 18432;
  const float* src = (wsel == 0) ? wq : (wsel == 1) ? wk : (wsel == 2) ? wv : wo;
  u16* dst = (wsel == 0) ? wqb : (wsel == 1) ? wkb : (wsel == 2) ? wvb : wob;
  const float4* p = reinterpret_cast<const float4*>(src + (size_t)off * 8);
  float4 lo = p[0], hi = p[1];
  *reinterpret_cast<uint4*>(dst + (size_t)off * 8) = pack8(lo, hi);
}

// ---------------------------------------------------------------------------
// Fused QKV projection — round 19: A read DIRECTLY from fp32 X with
// in-register pack (deletes the prep-X pass: -24MB HBM traffic).
// Attn-proven dbuf skeleton: compute(i) -> barrier -> {ds_write packed
// A(i+2), issue B gl_lds(i+2), prefetch A-loads(i+3)}.  A-loads get TWO
// compute phases of flight; pack8 rounding identical to prep -> outputs
// bit-identical.  BK=32, 40KB LDS, (256,3).
// ---------------------------------------------------------------------------
#define QKV_SBUF 10240   // u16 per buffer (20KB)

__global__ __launch_bounds__(256, 3) void qkv_fused(
    const float* __restrict__ Xf,
    const u16* __restrict__ Wqb, const u16* __restrict__ Wkb, const u16* __restrict__ Wvb,
    const float* __restrict__ cosb, const float* __restrict__ sinb,
    u16* __restrict__ Qo, u16* __restrict__ Ko, u16* __restrict__ Vto)
{
  __shared__ __align__(16) u16 smem[2 * QKV_SBUF];   // 40 KB (epilogue: 18KB)

  // XCD remap: 768 wgs = 8 xcds x (16 m-blocks x 6 heads)
  const int id = blockIdx.x;
  const int xcd = id & 7;
  const int s = id >> 3;              // 0..95
  const int mb = xcd * 16 + s / 6;    // 0..127
  const int hh = s % 6;
  const int m0 = mb * 128;
  const int n0 = hh * 64;

  const int tid = threadIdx.x;
  const int w = tid >> 6;
  const int lane = tid & 63;
  const int quad = lane >> 4;
  const int c = lane & 15;

  const u16* Wz[3] = {Wqb, Wkb, Wvb};

  floatx4 acc[3][2][4];
#pragma unroll
  for (int z = 0; z < 3; z++)
#pragma unroll
    for (int i = 0; i < 2; i++)
#pragma unroll
      for (int j = 0; j < 4; j++) acc[z][i][j] = (floatx4){0.f, 0.f, 0.f, 0.f};

  const int lrow = lane >> 2;        // row within a 16-row chunk
  const int lcol = (lane & 3) * 8;   // 8-col (16B) offset within 32 cols

  // A: fp32 loads into regs (2 chunks/lane: 4 float4)
  float4 ar[2][2];
  auto LOADA = [&](int k0) {
#pragma unroll
    for (int n = 0; n < 2; n++) {
      const int ch = w * 2 + n;
      const float* p = Xf + (size_t)(m0 + ch * 16 + lrow) * C_ + k0 + lcol;
      ar[n][0] = *reinterpret_cast<const float4*>(p);
      ar[n][1] = *reinterpret_cast<const float4*>(p + 4);
    }
  };
  auto WRITEA = [&](int bb) {   // pack + ds_write (16B aligned: lcol mult of 8 u16)
    u16* base = smem + bb * QKV_SBUF;
#pragma unroll
    for (int n = 0; n < 2; n++) {
      const int ch = w * 2 + n;
      *reinterpret_cast<uint4*>(base + ch * 512 + lrow * 32 + lcol) =
          pack8(ar[n][0], ar[n][1]);
    }
  };
  auto STAGEB = [&](int bb, int k0) {   // 3 gl_lds16 per lane
    u16* base = smem + bb * QKV_SBUF;
#pragma unroll
    for (int n = 0; n < 3; n++) {
      const int idx = w * 3 + n;       // 0..11
      const int z = idx >> 2;
      const int chz = idx & 3;
      gl_lds16(Wz[z] + (size_t)(n0 + chz * 16 + lrow) * C_ + k0 + lcol,
               base + 4096 + z * 2048 + chz * 512);
    }
  };

  // prologue: tiles 0 and 1 staged; A(2) prefetched
  LOADA(0);
  WRITEA(0);
  STAGEB(0, 0);
  LOADA(32);
  WRITEA(1);
  STAGEB(1, 32);
  LOADA(64);
  __syncthreads();   // full drain: buf0 AND buf1 ready

  for (int i = 0; i < 12; i++) {
    const u16* As = smem + (i & 1) * QKV_SBUF;
    const u16* Bs0 = As + 4096;
    __builtin_amdgcn_s_setprio(1);
    short8 af2[2];
#pragma unroll
    for (int mi = 0; mi < 2; mi++)
      af2[mi] = *reinterpret_cast<const short8*>(
          As + (w * 32 + mi * 16 + c) * 32 + quad * 8);
#pragma unroll
    for (int z = 0; z < 3; z++) {
#pragma unroll
      for (int ni = 0; ni < 4; ni++) {
        short8 bf = *reinterpret_cast<const short8*>(
            Bs0 + z * 2048 + (ni * 16 + c) * 32 + quad * 8);
#pragma unroll
        for (int mi = 0; mi < 2; mi++)
          acc[z][mi][ni] = __builtin_amdgcn_mfma_f32_16x16x32_bf16(af2[mi], bf, acc[z][mi][ni], 0, 0, 0);
      }
    }
    __builtin_amdgcn_s_setprio(0);

    __syncthreads();   // all waves done reading buf[i&1]; drains tile i+1's stages
    if (i + 2 < 12) {
      WRITEA(i & 1);                   // tile i+2 into just-freed buffer
      STAGEB(i & 1, (i + 2) * 32);
      if (i + 3 < 12) LOADA((i + 3) * 32);
    }
  }

  const int bb2 = m0 >> 11;
  const int tbase = m0 & (T_ - 1);

  // ---- V: register scatter to Vt[B][H][D][T] ----
  {
    const size_t vbase = ((size_t)(bb2 * H_ + hh)) * D_ * T_;
#pragma unroll
    for (int mi = 0; mi < 2; mi++) {
      int t = tbase + w * 32 + mi * 16 + quad * 4;
#pragma unroll
      for (int ni = 0; ni < 4; ni++) {
        int d = ni * 16 + c;
        ushort4 pk;
        pk.x = f2b(acc[2][mi][ni][0]); pk.y = f2b(acc[2][mi][ni][1]);
        pk.z = f2b(acc[2][mi][ni][2]); pk.w = f2b(acc[2][mi][ni][3]);
        *reinterpret_cast<ushort4*>(Vto + vbase + (size_t)d * T_ + t) = pk;
      }
    }
  }

  // ---- Q then K: lane-parallel RMS + RoPE, LDS transpose store ----
  u16* Ep = smem;
#pragma unroll
  for (int zz = 0; zz < 2; zz++) {
    __syncthreads();
#pragma unroll
    for (int mi = 0; mi < 2; mi++) {
      float ssr[4];
#pragma unroll
      for (int r = 0; r < 4; r++) {
        float s0 = acc[zz][mi][0][r], s1 = acc[zz][mi][1][r];
        float s2 = acc[zz][mi][2][r], s3 = acc[zz][mi][3][r];
        ssr[r] = s0 * s0 + s1 * s1 + s2 * s2 + s3 * s3;
      }
#pragma unroll
      for (int off = 1; off < 16; off <<= 1)
#pragma unroll
        for (int r = 0; r < 4; r++) ssr[r] += __shfl_xor(ssr[r], off, 64);
      int rowb = w * 32 + mi * 16 + quad * 4;
#pragma unroll
      for (int r = 0; r < 4; r++) {
        float scl = rsqrtf(ssr[r] * (1.0f / 64.0f) + 1e-5f);
        if (zz == 0) scl *= QSCALE;     // fold softmax scale into Q
        int t = tbase + rowb + r;
#pragma unroll
        for (int h2 = 0; h2 < 2; h2++) {
          float cs = cosb[t * 32 + h2 * 16 + c];
          float sn = sinb[t * 32 + h2 * 16 + c];
          float x1 = acc[zz][mi][h2][r];
          float x2 = acc[zz][mi][h2 + 2][r];
          Ep[(rowb + r) * 72 + h2 * 16 + c]       = f2b((x1 * cs + x2 * sn) * scl);
          Ep[(rowb + r) * 72 + (h2 + 2) * 16 + c] = f2b((x2 * cs - x1 * sn) * scl);
        }
      }
    }
    __syncthreads();
    {
      int row = tid >> 1, half = tid & 1;
      int t = tbase + row;
      u16* Og = (zz == 0) ? Qo : Ko;
      u16* dst = Og + (((size_t)(bb2 * H_ + hh)) * T_ + t) * D_ + half * 32;
#pragma unroll
      for (int i = 0; i < 4; i++)
        *reinterpret_cast<uint4*>(dst + i * 8) =
            *reinterpret_cast<const uint4*>(Ep + row * 72 + half * 32 + i * 8);
    }
  }
}

// ---------------------------------------------------------------------------
// MFMA flash attention — proven config (63.3-64.9us): stride-72 layout,
// identity slots, l ones-MFMA interleaved into PV, setprio.  UNTOUCHED.
// ---------------------------------------------------------------------------
#define ATT_LDA 72        // u16 row stride (144 B, 16B-aligned, bank-rotating)
#define ATT_VOFF 4608     // 64 rows * 72
#define ATT_BUF 9216      // K+V plane per buffer (u16)

__global__ __launch_bounds__(256, 3) void attn_mfma(
    const u16* __restrict__ Qg, const u16* __restrict__ Kg,
    const u16* __restrict__ Vtg, u16* __restrict__ Yg)
{
  __shared__ __align__(16) u16 smem[2 * ATT_BUF];   // 36864 B

  const int tid = threadIdx.x;
  const int w = tid >> 6;
  const int lane = tid & 63;
  const int hi = lane >> 5;
  const int lq = lane & 31;

  // XCD remap: 768 wgs = 8 xcds x (6 bh x 16 q-blocks)
  const int id = blockIdx.x;
  const int xcd = id & 7;
  const int slot = id >> 3;              // 0..95
  const int bh = xcd * 6 + (slot >> 4);  // 0..47
  const int q0 = (slot & 15) * 128;

  const size_t baseQK = (size_t)bh * T_ * D_;
  const size_t baseV  = (size_t)bh * D_ * T_;

  // Q fragments (B-operand): lane holds Q[q0+w*32+lq][ds*16 + hi*8 + j]
  short8 qf[4];
  {
    const u16* qp = Qg + baseQK + (size_t)(q0 + w * 32 + lq) * D_ + hi * 8;
#pragma unroll
    for (int d = 0; d < 4; d++)
      qf[d] = *reinterpret_cast<const short8*>(qp + d * 16);
  }

  floatx16 z16;
#pragma unroll
  for (int i = 0; i < 16; i++) z16[i] = 0.f;
  short8 vones;
#pragma unroll
  for (int i = 0; i < 8; i++) vones[i] = (short)0x3F80;

  // staging: 256 threads cover 64 rows x 2 x 16B chunks; identity slots
  const int sr = tid >> 2;
  const int sch = tid & 3;
  const int ko0 = sr * ATT_LDA + sch * 8;
  const int ko1 = sr * ATT_LDA + (sch + 4) * 8;
  const int vo0 = ATT_VOFF + ko0;
  const int vo1 = ATT_VOFF + ko1;
  const u16* kga = Kg + baseQK + (size_t)sr * D_ + sch * 8;
  const u16* vga = Vtg + baseV + (size_t)sr * T_ + sch * 8;

  // prologue: tile 0 -> regs -> buf0; then prefetch tile 1 into regs
  uint4 ka = *reinterpret_cast<const uint4*>(kga);
  uint4 kb = *reinterpret_cast<const uint4*>(kga + 32);
  uint4 va = *reinterpret_cast<const uint4*>(vga);
  uint4 vb = *reinterpret_cast<const uint4*>(vga + 32);
  *reinterpret_cast<uint4*>(smem + ko0) = ka;
  *reinterpret_cast<uint4*>(smem + ko1) = kb;
  *reinterpret_cast<uint4*>(smem + vo0) = va;
  *reinterpret_cast<uint4*>(smem + vo1) = vb;
  const u16* kload = kga + (size_t)64 * D_;
  const u16* vload = vga + 64;
  ka = *reinterpret_cast<const uint4*>(kload);
  kb = *reinterpret_cast<const uint4*>(kload + 32);
  va = *reinterpret_cast<const uint4*>(vload);
  vb = *reinterpret_cast<const uint4*>(vload + 32);
  kload += (size_t)64 * D_;
  vload += 64;

  floatx16 o0 = z16, o1 = z16;
  floatx16 l_acc = z16;

  // hoisted thread-invariant LDS read offsets (identity slots)
  int koff[2][4], voff[2][4];
#pragma unroll
  for (int ds = 0; ds < 4; ds++) {
    const int xr = ds * 2 + hi;
    koff[0][ds] = lq * ATT_LDA + xr * 8;
    koff[1][ds] = (32 + lq) * ATT_LDA + xr * 8;
    voff[0][ds] = ATT_VOFF + lq * ATT_LDA + xr * 8;
    voff[1][ds] = ATT_VOFF + (32 + lq) * ATT_LDA + xr * 8;
  }

  for (int kt = 0; kt < 32; kt++) {
    __syncthreads();   // buf[kt&1] fully written; buf[(kt+1)&1] fully read

    // write prefetched tile kt+1 into the other buffer; issue loads kt+2
    if (kt < 31) {
      u16* wb = smem + ((kt + 1) & 1) * ATT_BUF;
      *reinterpret_cast<uint4*>(wb + ko0) = ka;
      *reinterpret_cast<uint4*>(wb + ko1) = kb;
      *reinterpret_cast<uint4*>(wb + vo0) = va;
      *reinterpret_cast<uint4*>(wb + vo1) = vb;
      if (kt < 30) {
        ka = *reinterpret_cast<const uint4*>(kload);
        kb = *reinterpret_cast<const uint4*>(kload + 32);
        va = *reinterpret_cast<const uint4*>(vload);
        vb = *reinterpret_cast<const uint4*>(vload + 32);
        kload += (size_t)64 * D_;
        vload += 64;
      }
    }

    const u16* Ksb = smem + (kt & 1) * ATT_BUF;

    // ---- QK^T (swapped): st = K * Q^T, col = q (lane-local), rows = t ----
    floatx16 st0, st1;
    __builtin_amdgcn_s_setprio(1);
    {
      short8 kf0 = *reinterpret_cast<const short8*>(Ksb + koff[0][0]);
      short8 kf1 = *reinterpret_cast<const short8*>(Ksb + koff[1][0]);
      st0 = __builtin_amdgcn_mfma_f32_32x32x16_bf16(kf0, qf[0], z16, 0, 0, 0);
      st1 = __builtin_amdgcn_mfma_f32_32x32x16_bf16(kf1, qf[0], z16, 0, 0, 0);
    }
#pragma unroll
    for (int ds = 1; ds < 4; ds++) {
      short8 kf0 = *reinterpret_cast<const short8*>(Ksb + koff[0][ds]);
      short8 kf1 = *reinterpret_cast<const short8*>(Ksb + koff[1][ds]);
      st0 = __builtin_amdgcn_mfma_f32_32x32x16_bf16(kf0, qf[ds], st0, 0, 0, 0);
      st1 = __builtin_amdgcn_mfma_f32_32x32x16_bf16(kf1, qf[ds], st1, 0, 0, 0);
    }
    __builtin_amdgcn_s_setprio(0);

    // ---- softmax: p = exp2(s), bare v_exp_f32 ----
#pragma unroll
    for (int r = 0; r < 16; r++) {
      st0[r] = fexp2(st0[r]);
      st1[r] = fexp2(st1[r]);
    }

    // ---- P -> bf16 A-fragments: 16 v_cvt_pk + 8 permlane32_swap ----
    short8 pa[4];
#pragma unroll
    for (int ks = 0; ks < 4; ks++) {
      const floatx16& s = (ks < 2) ? st0 : st1;
      const int rb = (ks & 1) * 8;
      u32 ca = cvtpk(s[rb + 0], s[rb + 1]);
      u32 cb = cvtpk(s[rb + 2], s[rb + 3]);
      u32 cc = cvtpk(s[rb + 4], s[rb + 5]);
      u32 cd = cvtpk(s[rb + 6], s[rb + 7]);
      plswap(ca, cc);
      plswap(cb, cd);
      short8 pf;
      u32* pfu = reinterpret_cast<u32*>(&pf);
      pfu[0] = ca; pfu[1] = cb; pfu[2] = cc; pfu[3] = cd;
      pa[ks] = pf;
    }

    // ---- PV + l row-sums: 3 independent chains (o0/o1/l) interleaved ----
    __builtin_amdgcn_s_setprio(1);
#pragma unroll
    for (int ks = 0; ks < 4; ks++) {
      short8 vf0 = *reinterpret_cast<const short8*>(Ksb + voff[0][ks]);
      short8 vf1 = *reinterpret_cast<const short8*>(Ksb + voff[1][ks]);
      o0 = __builtin_amdgcn_mfma_f32_32x32x16_bf16(pa[ks], vf0, o0, 0, 0, 0);
      o1 = __builtin_amdgcn_mfma_f32_32x32x16_bf16(pa[ks], vf1, o1, 0, 0, 0);
      l_acc = __builtin_amdgcn_mfma_f32_32x32x16_bf16(pa[ks], vones, l_acc, 0, 0, 0);
    }
    __builtin_amdgcn_s_setprio(0);
  }

  // normalization: l_acc[r] holds l for exactly the q-row o[r] holds
  float invr[16];
#pragma unroll
  for (int r = 0; r < 16; r++) invr[r] = __builtin_amdgcn_rcpf(l_acc[r]);

  __syncthreads();   // done with K/V buffers; reuse smem for epilogue
  u16* Ep = smem + w * (32 * 72);
#pragma unroll
  for (int nt = 0; nt < 2; nt++) {
    const floatx16& o = nt ? o1 : o0;
#pragma unroll
    for (int r = 0; r < 16; r++) {
      const int rl = (r & 3) + 8 * (r >> 2) + 4 * hi;
      Ep[rl * 72 + nt * 32 + lq] = f2b(o[r] * invr[r]);
    }
  }
  __syncthreads();
  {
    const int row = tid >> 1, half = tid & 1;   // 128 rows x 2 halves of 64B
    const u16* src = smem + (row >> 5) * (32 * 72) + (row & 31) * 72 + half * 32;
    const int t = q0 + row;
    const int b = bh / H_, h = bh % H_;
    const size_t yi = ((size_t)b * T_ + t) * C_ + (size_t)h * 64 + half * 32;
#pragma unroll
    for (int i = 0; i < 4; i++)
      *reinterpret_cast<uint4*>(Yg + yi + i * 8) =
          *reinterpret_cast<const uint4*>(src + i * 8);
  }
}

// ---------------------------------------------------------------------------
// Out projection — round-18 passed config: BK=32 dbuf + counted-vmcnt raw
// barriers (3 gl_lds16 per lane per STAGE -> vmcnt(3)).
// ---------------------------------------------------------------------------
#define OUT_SBUF 6144    // u16 per buffer (12KB)

__global__ __launch_bounds__(256, 4) void out_mfma(
    const u16* __restrict__ Xb, const u16* __restrict__ Wfb, float* __restrict__ Og)
{
  __shared__ __align__(16) u16 smem[17408];   // buffers at 0/6144; fp32 Ep 34816B

  const int id = blockIdx.x;
  const int xcd = id & 7;
  const int s = id >> 3;              // 0..95
  const int m0 = (xcd * 16 + s / 6) * 128;
  const int n0 = (s % 6) * 64;

  const int tid = threadIdx.x;
  const int w = tid >> 6;
  const int lane = tid & 63;
  const int quad = lane >> 4;
  const int c = lane & 15;

  floatx4 acc[2][4];
#pragma unroll
  for (int i = 0; i < 2; i++)
#pragma unroll
    for (int j = 0; j < 4; j++) acc[i][j] = (floatx4){0.f, 0.f, 0.f, 0.f};

  const int lrow = lane >> 2;        // row within a 16-row chunk
  const int lcol = (lane & 3) * 8;   // 8-col offset within 32 cols

  auto STAGE = [&](int bb, int k0) {
    u16* base = smem + bb * OUT_SBUF;
#pragma unroll
    for (int n = 0; n < 2; n++) {
      const int ch = w * 2 + n;
      gl_lds16(Xb + (size_t)(m0 + ch * 16 + lrow) * C_ + k0 + lcol, base + ch * 512);
    }
    gl_lds16(Wfb + (size_t)(n0 + w * 16 + lrow) * C_ + k0 + lcol,
             base + 4096 + w * 512);
  };

  STAGE(0, 0);       // 3 outstanding
  STAGE(1, 32);      // 6 outstanding

  for (int i = 0; i < 12; i++) {
    if (i < 11) asm volatile("s_waitcnt vmcnt(3)" ::: "memory");
    else        asm volatile("s_waitcnt vmcnt(0)" ::: "memory");
    rawbar();

    const u16* As = smem + (i & 1) * OUT_SBUF;
    const u16* Bs = As + 4096;
    __builtin_amdgcn_s_setprio(1);
    short8 af[2], bf[4];
#pragma unroll
    for (int mi = 0; mi < 2; mi++)
      af[mi] = *reinterpret_cast<const short8*>(
          As + (w * 32 + mi * 16 + c) * 32 + quad * 8);
#pragma unroll
    for (int ni = 0; ni < 4; ni++)
      bf[ni] = *reinterpret_cast<const short8*>(
          Bs + (ni * 16 + c) * 32 + quad * 8);
#pragma unroll
    for (int mi = 0; mi < 2; mi++)
#pragma unroll
      for (int ni = 0; ni < 4; ni++)
        acc[mi][ni] = __builtin_amdgcn_mfma_f32_16x16x32_bf16(af[mi], bf[ni], acc[mi][ni], 0, 0, 0);
    __builtin_amdgcn_s_setprio(0);

    rawbar();
    if (i + 2 < 12) STAGE(i & 1, (i + 2) * 32);
  }

  __syncthreads();
  float* Ep = reinterpret_cast<float*>(smem) + w * (32 * 68);
#pragma unroll
  for (int mi = 0; mi < 2; mi++)
#pragma unroll
    for (int ni = 0; ni < 4; ni++) {
      int rw = mi * 16 + quad * 4;
      int col = ni * 16 + c;
#pragma unroll
      for (int r = 0; r < 4; r++)
        Ep[(rw + r) * 68 + col] = acc[mi][ni][r];
    }
  __syncthreads();
  {
    int rw2 = lane >> 1, half = lane & 1;
    const float* src = Ep + rw2 * 68 + half * 32;
    float* dst = Og + (size_t)(m0 + w * 32 + rw2) * C_ + n0 + half * 32;
#pragma unroll
    for (int i = 0; i < 8; i++)
      *reinterpret_cast<float4*>(dst + i * 4) =
          *reinterpret_cast<const float4*>(src + i * 4);
  }
}

// ---------------------------------------------------------------------------
extern "C" void kernel_launch(void* const* d_in, const int* in_sizes, int n_in,
                              void* d_out, int out_size, void* d_ws, size_t ws_size,
                              hipStream_t stream) {
  (void)in_sizes; (void)n_in; (void)out_size; (void)ws_size;
  const float* x    = (const float*)d_in[0];
  const float* Wq   = (const float*)d_in[1];
  const float* Wk   = (const float*)d_in[2];
  const float* Wv   = (const float*)d_in[3];
  const float* Wo   = (const float*)d_in[4];
  const float* cosb = (const float*)d_in[5];
  const float* sinb = (const float*)d_in[6];

  const size_t MC = (size_t)M_ * C_;    // 6291456
  u16* ws = (u16*)d_ws;
  u16* Q   = ws;                        // [B][H][T][D] bf16 (pre-scaled)
  u16* K   = Q + MC;
  u16* Vt  = K + MC;                    // [B][H][D][T] bf16
  u16* Y   = Vt + MC;                   // attn out [B*T][C] bf16
  u16* Wb  = Y + MC;                    // 4 x 147456 bf16 weights
  u16* Wqb = Wb;
  u16* Wkb = Wb + 147456;
  u16* Wvb = Wb + 2 * 147456;
  u16* Wob = Wb + 3 * 147456;
  float* out = (float*)d_out;

  prep_w<<<288, 256, 0, stream>>>(Wq, Wk, Wv, Wo, Wqb, Wkb, Wvb, Wob);

  qkv_fused<<<768, 256, 0, stream>>>(x, Wqb, Wkb, Wvb, cosb, sinb, Q, K, Vt);

  attn_mfma<<<768, 256, 0, stream>>>(Q, K, Vt, Y);

  out_mfma<<<768, 256, 0, stream>>>(Y, Wob, out);
}